// Round 7
// baseline (604.588 us; speedup 1.0000x reference)
//
#include <hip/hip_runtime.h>
#include <hip/hip_bf16.h>
#include <cstdint>
#include <cstddef>

// S4D-PLR transition model, MI355X (gfx950).
// R10: gemmC switched to BARRIER-FREE 1-wave 64x64 tiles (gemm_w64): each
// wave privately stages 64x32 A/B slices (16KB LDS, 2 buffers) and paces
// itself with per-wave vmcnt(8) (depth-2 with 2 buffers: refill buf p right
// after lgkm-drain of its reads; refill lands 2 steps later). ~10 independent
// waves/CU, zero s_barrier. R9 A/B showed blocks-resident is the lever
// (37.5% occ -> -14% vs uncapped); this removes the 4-wave lockstep itself.
// gemmA/gemmB keep the proven 3-buffer barrier core (within-run A/B control).

typedef __bf16 bf16;
typedef __bf16 bf16x8 __attribute__((ext_vector_type(8)));
typedef __bf16 bf16x4 __attribute__((ext_vector_type(4)));
typedef float f32x4 __attribute__((ext_vector_type(4)));

// ---------------------------------------------------------------- async copy
__device__ __forceinline__ void async16(const void* g, void* l) {
  __builtin_amdgcn_global_load_lds((const __attribute__((address_space(1))) void*)g,
                                   (__attribute__((address_space(3))) void*)l, 16, 0, 0);
}

// ---------------------------------------------------------------- tile maps
__device__ __forceinline__ bool tile_map(int NT, int& m0, int& n0) {
  int L = blockIdx.x;                       // 128x128 tiles, 16 m-tiles
  int x = L & 7, s = L >> 3;
  int nt = ((s >> 4) << 3) + x;
  if (nt >= NT) return false;
  n0 = nt << 7;
  m0 = (s & 15) << 7;
  return true;
}

// 64x64 tiles, 32 m-tiles. 12800 blocks for NT=400 (exact, no padding).
__device__ __forceinline__ void tile_map64(int& m0, int& n0) {
  int L = blockIdx.x;
  int x = L & 7, s = L >> 3;
  int nt = ((s >> 5) << 3) + x;
  n0 = nt << 6;
  m0 = (s & 31) << 6;
}

// ---------------------------------------------------------------- GEMM cores
// Swizzle (verified): staging chunk c holds row c>>2, k-chunk (c&3)^((r>>1)&3);
// reader row R, k-half q reads elems R*32 + ((q^((R>>1)&3))<<3); since
// R = base16 + fr, (R>>1)&3 == (fr>>1)&3. Conflict-free (counters: 0).

// 3-buffer, 4-wave, depth-2, vmcnt(4) pacing (best measured: R6/R9-A).
__device__ __forceinline__ void gemm_p3(const bf16* __restrict__ A,
                                        const bf16* __restrict__ Bw,
                                        int m0, int n0,
                                        bf16* lds, f32x4 acc[4][4]) {
  const int tid = threadIdx.x;
  const int w = tid >> 6, l = tid & 63;
  const int wm = (w >> 1) << 6, wn = (w & 1) << 6;
  const int fr = l & 15, q = l >> 4;

  const int c0 = tid, c1 = tid + 256;
  const int r0 = c0 >> 2, k0 = ((c0 & 3) ^ ((r0 >> 1) & 3)) << 3;
  const int r1 = c1 >> 2, k1 = ((c1 & 3) ^ ((r1 >> 1) & 3)) << 3;
  const bf16* a0 = A + (size_t)(m0 + r0) * 512 + k0;
  const bf16* a1 = A + (size_t)(m0 + r1) * 512 + k1;
  const bf16* b0 = Bw + (size_t)(n0 + r0) * 512 + k0;
  const bf16* b1 = Bw + (size_t)(n0 + r1) * 512 + k1;
  const int sw = (q ^ ((fr >> 1) & 3)) << 3;

#pragma unroll
  for (int mt = 0; mt < 4; ++mt)
#pragma unroll
    for (int nt = 0; nt < 4; ++nt) { f32x4 z = {0.f, 0.f, 0.f, 0.f}; acc[mt][nt] = z; }

  auto issue = [&](int kt, int p) {
    bf16* d = lds + p * 8192;
    async16(a0 + kt, d + (c0 << 3));
    async16(a1 + kt, d + (c1 << 3));
    async16(b0 + kt, d + 4096 + (c0 << 3));
    async16(b1 + kt, d + 4096 + (c1 << 3));
  };

  issue(0, 0);
  issue(32, 1);
#pragma unroll
  for (int it = 0; it < 16; ++it) {
    const int p = it % 3;
    if (it < 14) asm volatile("s_waitcnt vmcnt(4)" ::: "memory");  // buf it landed
    else         asm volatile("s_waitcnt vmcnt(0)" ::: "memory");
    asm volatile("s_barrier" ::: "memory");
    if (it + 2 < 16) issue((it + 2) << 5, (it + 2) % 3);  // WAR-safe post-barrier
    const bf16* ab = lds + p * 8192;
    const bf16* bb = ab + 4096;
    bf16x8 af[4], bfv[4];
#pragma unroll
    for (int mt = 0; mt < 4; ++mt)
      af[mt] = *(const bf16x8*)(ab + (wm + mt * 16 + fr) * 32 + sw);
#pragma unroll
    for (int nt = 0; nt < 4; ++nt)
      bfv[nt] = *(const bf16x8*)(bb + (wn + nt * 16 + fr) * 32 + sw);
#pragma unroll
    for (int mt = 0; mt < 4; ++mt)
#pragma unroll
      for (int nt = 0; nt < 4; ++nt)
        acc[mt][nt] = __builtin_amdgcn_mfma_f32_16x16x32_bf16(af[mt], bfv[nt],
                                                              acc[mt][nt], 0, 0, 0);
    asm volatile("s_waitcnt lgkmcnt(0)" ::: "memory");   // reads done pre-barrier
  }
}

// 1-wave 64x64 core: barrier-free, per-wave vmcnt pacing, 2 buffers depth-2.
// LDS buf p at p*4096 elems: A 64x32 at +0 (2048), B 64x32 at +2048.
// Thread t stages 4 A-chunks {t,t+64,t+128,t+192} and 4 B-chunks; chunk
// c = t+64i has row r0+16i, SAME k-chunk k0 (since (r>>1)&3 is 16-periodic).
__device__ __forceinline__ void gemm_w64(const bf16* __restrict__ A,
                                         const bf16* __restrict__ Bw,
                                         int m0, int n0,
                                         bf16* lds, f32x4 acc[4][4]) {
  const int t = threadIdx.x;                // 0..63
  const int fr = t & 15, q = t >> 4;
  const int r0 = t >> 2, k0 = ((t & 3) ^ ((r0 >> 1) & 3)) << 3;
  const bf16* ag = A + (size_t)(m0 + r0) * 512 + k0;
  const bf16* bg = Bw + (size_t)(n0 + r0) * 512 + k0;
  const int sw = (q ^ ((fr >> 1) & 3)) << 3;

#pragma unroll
  for (int mt = 0; mt < 4; ++mt)
#pragma unroll
    for (int nt = 0; nt < 4; ++nt) { f32x4 z = {0.f, 0.f, 0.f, 0.f}; acc[mt][nt] = z; }

  auto issue = [&](int kt, int p) {
    bf16* d = lds + p * 4096;
#pragma unroll
    for (int i = 0; i < 4; ++i) {           // A: rows r0+16i, +16KB strides
      async16(ag + (size_t)i * 16 * 512 + kt, d + (t << 3) + i * 512);
      async16(bg + (size_t)i * 16 * 512 + kt, d + 2048 + (t << 3) + i * 512);
    }
  };

  issue(0, 0);
  issue(32, 1);
#pragma unroll
  for (int it = 0; it < 16; ++it) {
    const int p = it & 1;
    if (it < 15) asm volatile("s_waitcnt vmcnt(8)" ::: "memory");  // buf it landed
    else         asm volatile("s_waitcnt vmcnt(0)" ::: "memory");
    const bf16* ab = lds + p * 4096;
    const bf16* bb = ab + 2048;
    bf16x8 af[4], bfv[4];
#pragma unroll
    for (int mt = 0; mt < 4; ++mt)
      af[mt] = *(const bf16x8*)(ab + (mt * 16 + fr) * 32 + sw);
#pragma unroll
    for (int nt = 0; nt < 4; ++nt)
      bfv[nt] = *(const bf16x8*)(bb + (nt * 16 + fr) * 32 + sw);
    asm volatile("s_waitcnt lgkmcnt(0)" ::: "memory");   // reads done -> WAR-safe
    if (it + 2 < 16) issue((it + 2) << 5, p);            // refill lands by it+2
#pragma unroll
    for (int mt = 0; mt < 4; ++mt)
#pragma unroll
      for (int nt = 0; nt < 4; ++nt)
        acc[mt][nt] = __builtin_amdgcn_mfma_f32_16x16x32_bf16(af[mt], bfv[nt],
                                                              acc[mt][nt], 0, 0, 0);
  }
}
// C/D layout (verified m89/m91): col = lane&15, row = (lane>>4)*4 + reg.

// ---------------------------------------------------------------- fused phase-0
// Block ranges: [0,6536) transpose | [6536,6741) bias gather |
// [6741,7797) zero tbuf+lr | [7797,8821) lin0.
struct TEntry { const float* src; bf16* dst; int N, tile0, ntn; };
struct P0Args {
  TEntry e[11];
  const float *ba, *bo, *bVr, *bVi, *bBr, *bBi, *bD, *bUr, *bUi, *bCr, *bCi;
  float *bbigA, *bbigB, *bbigC;
  float *tbuf, *lr;
  const float *zt, *dt, *ut, *W0, *b0;
  float* s0;
};

__global__ void k_p0(P0Args a) {
  __shared__ float tile[64][65];
  const int blk = blockIdx.x;
  const int tid = threadIdx.x;

  if (blk < 6536) {                                   // ---- weight transpose
    int t = blk;
    int ei = 0;
    while (ei < 10 && t >= a.e[ei + 1].tile0) ++ei;
    const TEntry E = a.e[ei];
    int lt = t - E.tile0;
    int tk = lt / E.ntn, tn = lt - tk * E.ntn;
    int k0 = tk << 6, n0 = tn << 6;
#pragma unroll
    for (int i = 0; i < 4; ++i) {
      int idx = tid + i * 256;
      int kk = idx >> 4, c4 = (idx & 15) << 2;
      const float4 v = *(const float4*)(E.src + (size_t)(k0 + kk) * E.N + n0 + c4);
      tile[c4 + 0][kk] = v.x; tile[c4 + 1][kk] = v.y;
      tile[c4 + 2][kk] = v.z; tile[c4 + 3][kk] = v.w;
    }
    __syncthreads();
#pragma unroll
    for (int i = 0; i < 4; ++i) {
      int idx = tid + i * 256;
      int nn = idx >> 4, k4 = (idx & 15) << 2;
      bf16x4 o;
      o[0] = (bf16)tile[nn][k4 + 0]; o[1] = (bf16)tile[nn][k4 + 1];
      o[2] = (bf16)tile[nn][k4 + 2]; o[3] = (bf16)tile[nn][k4 + 3];
      *(bf16x4*)(E.dst + (size_t)(n0 + nn) * 512 + k0 + k4) = o;
    }
  } else if (blk < 6741) {                            // ---- bias gather
    int i = (blk - 6536) * 256 + tid;
    if (i < 22656) {
      float v;
      if (i < 256) v = a.ba[i];
      else if (i < 512) v = a.bo[i - 256];
      else if (i < 2560) v = a.bVr[i - 512];
      else if (i < 4608) v = a.bVi[i - 2560];
      else if (i < 12800) v = a.bBr[i - 4608];
      else if (i < 20992) v = a.bBi[i - 12800];
      else if (i < 22592) v = a.bD[i - 20992];
      else v = 0.f;
      a.bbigA[i] = v;
    }
    int j = i - 22656;
    if (j >= 0 && j < 4096) a.bbigB[j] = (j < 2048) ? a.bUr[j] : a.bUi[j - 2048];
    int m = i - (22656 + 4096);
    if (m >= 0 && m < 25600) a.bbigC[m] = (m < 12800) ? a.bCr[m] : a.bCi[m - 12800];
  } else if (blk < 7797) {                            // ---- zero tbuf (8192 f4) + lr
    int idx = (blk - 6741) * 256 + tid;
    float4 z = {0.f, 0.f, 0.f, 0.f};
    if (idx < 8192) *(float4*)(a.tbuf + idx * 4) = z;
    else            *(float4*)(a.lr + (idx - 8192) * 4) = z;   // 262144 f4
  } else {                                            // ---- lin0 (selector layer 0)
    int i = (blk - 7797) * 256 + tid;                 // 2048*128
    int b = i >> 7, c = i & 127;
    const float* w = a.W0 + c;
    const float* x = a.zt + (size_t)b * 512;
    float a0 = a.b0[c], a1 = 0.f, a2 = 0.f, a3 = 0.f;
#pragma unroll 4
    for (int k = 0; k < 512; k += 4) {
      a0 = fmaf(x[k + 0], w[(size_t)(k + 0) * 128], a0);
      a1 = fmaf(x[k + 1], w[(size_t)(k + 1) * 128], a1);
      a2 = fmaf(x[k + 2], w[(size_t)(k + 2) * 128], a2);
      a3 = fmaf(x[k + 3], w[(size_t)(k + 3) * 128], a3);
    }
    const float* u = a.ut + (size_t)b * 32;
#pragma unroll
    for (int k = 0; k < 32; k += 4) {
      a0 = fmaf(u[k + 0], w[(size_t)(512 + k + 0) * 128], a0);
      a1 = fmaf(u[k + 1], w[(size_t)(512 + k + 1) * 128], a1);
      a2 = fmaf(u[k + 2], w[(size_t)(512 + k + 2) * 128], a2);
      a3 = fmaf(u[k + 3], w[(size_t)(512 + k + 3) * 128], a3);
    }
    a0 = fmaf(a.dt[b], w[(size_t)544 * 128], a0);
    a.s0[i] = (a0 + a1) + (a2 + a3);
  }
}

// ---------------------------------------------------------------- BN stats
__global__ void k_stats(const float* __restrict__ s, float* __restrict__ mu,
                        float* __restrict__ rstd) {
  int c = blockIdx.x;                           // 128 columns
  float sm = 0.f, sq = 0.f;
  for (int r = threadIdx.x; r < 2048; r += 256) {
    float v = s[(size_t)r * 128 + c];
    sm += v; sq += v * v;
  }
#pragma unroll
  for (int o = 32; o >= 1; o >>= 1) { sm += __shfl_down(sm, o); sq += __shfl_down(sq, o); }
  __shared__ float red[8];
  int w = threadIdx.x >> 6;
  if ((threadIdx.x & 63) == 0) { red[w] = sm; red[4 + w] = sq; }
  __syncthreads();
  if (threadIdx.x == 0) {
    float S = red[0] + red[1] + red[2] + red[3];
    float Q = red[4] + red[5] + red[6] + red[7];
    float m = S * (1.f / 2048.f);
    float var = Q * (1.f / 2048.f) - m * m;    // biased var (training-mode BN)
    mu[c] = m;
    rstd[c] = rsqrtf(var + 1e-5f);
  }
}

// ---------------------------------------------------------------- lin1/lin2 (inline BN)
__global__ void k_lin1(const float* __restrict__ s0, const float* __restrict__ mu,
                       const float* __restrict__ rstd, const float* __restrict__ g,
                       const float* __restrict__ be, const float* __restrict__ W1,
                       const float* __restrict__ b1, float* __restrict__ s1) {
  int i = blockIdx.x * 256 + threadIdx.x;      // 2048*128
  int b = i >> 7, c = i & 127;
  const float* w = W1 + c;
  const float* x = s0 + (size_t)b * 128;
  float a0 = b1[c], a1 = 0.f, a2 = 0.f, a3 = 0.f;
#pragma unroll 4
  for (int k = 0; k < 128; k += 4) {
    float h0 = fmaxf(fmaf((x[k + 0] - mu[k + 0]) * rstd[k + 0], g[k + 0], be[k + 0]), 0.f);
    float h1 = fmaxf(fmaf((x[k + 1] - mu[k + 1]) * rstd[k + 1], g[k + 1], be[k + 1]), 0.f);
    float h2 = fmaxf(fmaf((x[k + 2] - mu[k + 2]) * rstd[k + 2], g[k + 2], be[k + 2]), 0.f);
    float h3 = fmaxf(fmaf((x[k + 3] - mu[k + 3]) * rstd[k + 3], g[k + 3], be[k + 3]), 0.f);
    a0 = fmaf(h0, w[(size_t)(k + 0) * 128], a0);
    a1 = fmaf(h1, w[(size_t)(k + 1) * 128], a1);
    a2 = fmaf(h2, w[(size_t)(k + 2) * 128], a2);
    a3 = fmaf(h3, w[(size_t)(k + 3) * 128], a3);
  }
  s1[i] = (a0 + a1) + (a2 + a3);
}

__global__ void k_lin2(const float* __restrict__ s1, const float* __restrict__ mu,
                       const float* __restrict__ rstd, const float* __restrict__ g,
                       const float* __restrict__ be, const float* __restrict__ W2,
                       const float* __restrict__ b2, bf16* __restrict__ hz) {
  int i = blockIdx.x * 256 + threadIdx.x;      // 2048*512
  int b = i >> 9, c = i & 511;
  const float* w = W2 + c;
  const float* x = s1 + (size_t)b * 128;
  float a0 = b2[c], a1 = 0.f, a2 = 0.f, a3 = 0.f;
#pragma unroll 4
  for (int k = 0; k < 128; k += 4) {
    float h0 = fmaxf(fmaf((x[k + 0] - mu[k + 0]) * rstd[k + 0], g[k + 0], be[k + 0]), 0.f);
    float h1 = fmaxf(fmaf((x[k + 1] - mu[k + 1]) * rstd[k + 1], g[k + 1], be[k + 1]), 0.f);
    float h2 = fmaxf(fmaf((x[k + 2] - mu[k + 2]) * rstd[k + 2], g[k + 2], be[k + 2]), 0.f);
    float h3 = fmaxf(fmaf((x[k + 3] - mu[k + 3]) * rstd[k + 3], g[k + 3], be[k + 3]), 0.f);
    a0 = fmaf(h0, w[(size_t)(k + 0) * 512], a0);
    a1 = fmaf(h1, w[(size_t)(k + 1) * 512], a1);
    a2 = fmaf(h2, w[(size_t)(k + 2) * 512], a2);
    a3 = fmaf(h3, w[(size_t)(k + 3) * 512], a3);
  }
  hz[i] = (bf16)((a0 + a1) + (a2 + a3));
}

// ---------------------------------------------------------------- phase A GEMM
// columns: [0,256) a | [256,512) o | [512,2560) Vr | [2560,4608) Vi
//          [4608,12800) Br | [12800,20992) Bi | [20992,22592) D | pad to 22656
__global__ __launch_bounds__(256) void k_gemmA(
    const bf16* __restrict__ hz, const bf16* __restrict__ WT, const float* __restrict__ bias,
    const float* __restrict__ zt, const float* __restrict__ dt, const float* __restrict__ ut,
    float* __restrict__ pa, float* __restrict__ po,
    float* __restrict__ Bzr, float* __restrict__ Bzi,
    float* __restrict__ tbuf, float* __restrict__ ytout) {
  int m0, n0;
  if (!tile_map(177, m0, n0)) return;
  __shared__ __align__(16) bf16 lds[24576];
  f32x4 acc[4][4];
  gemm_p3(hz, WT, m0, n0, lds, acc);
  const int l = threadIdx.x & 63, w = threadIdx.x >> 6;
  const int wm = (w >> 1) << 6, wn = (w & 1) << 6;
  const int fr = l & 15, quad = l >> 4;
  const int ncol = n0 + wn;

  if (n0 < 512) {                                    // ---- a / o pre-acts
    float* dst = (n0 < 256) ? pa : po;
    int cb = ncol - ((n0 < 256) ? 0 : 256);
#pragma unroll
    for (int mt = 0; mt < 4; ++mt)
#pragma unroll
      for (int j = 0; j < 4; ++j) {
        int b = m0 + wm + mt * 16 + quad * 4 + j;
#pragma unroll
        for (int nt = 0; nt < 4; ++nt) {
          int n = ncol + nt * 16 + fr;
          dst[(size_t)b * 256 + (cb + nt * 16 + fr)] = acc[mt][nt][j] + bias[n];
        }
      }
  } else if (n0 < 4608) {                            // ---- V: t = conj(V)^T z
    const bool isVr = n0 < 2560;
#pragma unroll
    for (int mt = 0; mt < 4; ++mt)
#pragma unroll
      for (int j = 0; j < 4; ++j) {
        int b = m0 + wm + mt * 16 + quad * 4 + j;
        float cre = 0.f, cim = 0.f;
#pragma unroll
        for (int nt = 0; nt < 4; ++nt) {
          int n = ncol + nt * 16 + fr;
          float v = acc[mt][nt][j] + bias[n];
          int d = ((n - 512) & 2047) >> 3;
          float zr = zt[(size_t)b * 512 + d], zi = zt[(size_t)b * 512 + 256 + d];
          if (isVr) { cre += v * zr; cim += v * zi; }
          else      { cre += v * zi; cim -= v * zr; }
        }
        cre += __shfl_xor(cre, 8);
        cim += __shfl_xor(cim, 8);
        if ((l & 8) == 0) {
          int r = fr & 7;
          atomicAdd(&tbuf[((size_t)b * 8 + r) * 2 + 0], cre);
          atomicAdd(&tbuf[((size_t)b * 8 + r) * 2 + 1], cim);
        }
      }
  } else if (n0 < 20992) {                           // ---- B: Bz = Bt @ (ut*dt)
    const bool isBr = n0 < 12800;
    float* dst = isBr ? Bzr : Bzi;
#pragma unroll
    for (int mt = 0; mt < 4; ++mt)
#pragma unroll
      for (int j = 0; j < 4; ++j) {
        int b = m0 + wm + mt * 16 + quad * 4 + j;
        float dtb = dt[b];
#pragma unroll
        for (int g = 0; g < 2; ++g) {
          float s = 0.f;
#pragma unroll
          for (int h = 0; h < 2; ++h) {
            int nt = g * 2 + h;
            int n = ncol + nt * 16 + fr;
            int base = (n - 4608) & 8191;
            float v = acc[mt][nt][j] + bias[n];
            s += v * ut[(size_t)b * 32 + (base & 31)];
          }
          s *= dtb;
          s += __shfl_xor(s, 1); s += __shfl_xor(s, 2);
          s += __shfl_xor(s, 4); s += __shfl_xor(s, 8);
          if ((l & 15) == 0) {
            int d = (((ncol + g * 32) - 4608) & 8191) >> 5;
            dst[(size_t)b * 256 + d] = s;
          }
        }
      }
  } else {                                           // ---- D: yt init
#pragma unroll
    for (int mt = 0; mt < 4; ++mt)
#pragma unroll
      for (int j = 0; j < 4; ++j) {
        int b = m0 + wm + mt * 16 + quad * 4 + j;
        float dtb = dt[b];
#pragma unroll
        for (int g = 0; g < 2; ++g) {
          float s = 0.f;
#pragma unroll
          for (int h = 0; h < 2; ++h) {
            int nt = g * 2 + h;
            int n = ncol + nt * 16 + fr;
            int base = n - 20992;
            float v = acc[mt][nt][j] + bias[n];
            s += v * ut[(size_t)b * 32 + (base & 31)];
          }
          s *= dtb;
          s += __shfl_xor(s, 1); s += __shfl_xor(s, 2);
          s += __shfl_xor(s, 4); s += __shfl_xor(s, 8);
          int nn = ((ncol + g * 32) - 20992) >> 5;
          if ((l & 15) == 0 && nn < 50) ytout[(size_t)b * 50 + nn] = s;
        }
      }
  }
}

// ---------------------------------------------------------------- phase B GEMM (U)
__global__ __launch_bounds__(256) void k_gemmB(
    const bf16* __restrict__ hz, const bf16* __restrict__ WT, const float* __restrict__ bias,
    const float* __restrict__ tbuf, float* __restrict__ lr) {
  int m0, n0;
  if (!tile_map(32, m0, n0)) return;
  __shared__ __align__(16) bf16 lds[24576];
  f32x4 acc[4][4];
  gemm_p3(hz, WT, m0, n0, lds, acc);
  const int l = threadIdx.x & 63, w = threadIdx.x >> 6;
  const int wm = (w >> 1) << 6, wn = (w & 1) << 6;
  const int fr = l & 15, quad = l >> 4;
  const int ncol = n0 + wn;
  const bool isUr = n0 < 2048;
#pragma unroll
  for (int mt = 0; mt < 4; ++mt)
#pragma unroll
    for (int j = 0; j < 4; ++j) {
      int b = m0 + wm + mt * 16 + quad * 4 + j;
#pragma unroll
      for (int nt = 0; nt < 4; ++nt) {
        int n = ncol + nt * 16 + fr;
        int base = n & 2047;
        int r = base & 7, d = base >> 3;
        float v = acc[mt][nt][j] + bias[n];
        float tre = tbuf[((size_t)b * 8 + r) * 2], tim = tbuf[((size_t)b * 8 + r) * 2 + 1];
        float cre = isUr ? v * tre : -v * tim;
        float cim = isUr ? v * tim :  v * tre;
        cre += __shfl_xor(cre, 1); cre += __shfl_xor(cre, 2); cre += __shfl_xor(cre, 4);
        cim += __shfl_xor(cim, 1); cim += __shfl_xor(cim, 2); cim += __shfl_xor(cim, 4);
        if ((l & 7) == 0) {
          atomicAdd(&lr[((size_t)b * 256 + d) * 2 + 0], cre);
          atomicAdd(&lr[((size_t)b * 256 + d) * 2 + 1], cim);
        }
      }
    }
}

// ---------------------------------------------------------------- z_next assembly
__global__ void k_assembleZ(const float* __restrict__ zt, const float* __restrict__ pa,
                            const float* __restrict__ po, const float* __restrict__ Bzr,
                            const float* __restrict__ Bzi, const float* __restrict__ lr,
                            float* __restrict__ zout, float* __restrict__ znr,
                            float* __restrict__ zni) {
  int i = blockIdx.x * 256 + threadIdx.x;      // 2048*256
  int b = i >> 8, d = i & 255;
  float a = pa[i], o = po[i];
  float sp = fmaxf(a, 0.f) + log1pf(expf(-fabsf(a)));   // softplus, stable
  float mag = expf(-sp);
  float Lr = mag * cosf(o), Li = mag * sinf(o);
  float zr = zt[(size_t)b * 512 + d], zi = zt[(size_t)b * 512 + 256 + d];
  float re = fmaf(Lr, zr, -Li * zi) + Bzr[i] + lr[2 * i];
  float im = fmaf(Lr, zi,  Li * zr) + Bzi[i] + lr[2 * i + 1];
  zout[(size_t)b * 512 + d] = re;
  zout[(size_t)b * 512 + 256 + d] = im;
  znr[i] = re; zni[i] = im;
}

// ---------------------------------------------------------------- phase C GEMM (C)
// EXPERIMENT: barrier-free 1-wave 64x64 tiles. 12800 blocks of 64 threads;
// ~10 independent waves/CU (LDS 16KB/block). launch_bounds(64,3) caps regs
// at ~170 (est. need ~140 incl. 64 AGPR acc; no spill pressure).
__global__ __launch_bounds__(64, 3) void k_gemmC(
    const bf16* __restrict__ hz, const bf16* __restrict__ WT, const float* __restrict__ bias,
    const float* __restrict__ znr, const float* __restrict__ zni, float* __restrict__ ytout) {
  int m0, n0;
  tile_map64(m0, n0);                        // NT=400 exact, no invalid tiles
  __shared__ __align__(16) bf16 lds[8192];   // 2 bufs x (64x32 A + 64x32 B)
  f32x4 acc[4][4];
  gemm_w64(hz, WT, m0, n0, lds, acc);
  const int l = threadIdx.x;
  const int fr = l & 15, quad = l >> 4;
  const bool isCr = n0 < 12800;              // 12800 = 200*64, 64-aligned
  const int nb = n0 - (isCr ? 0 : 12800);
  const int nn = nb >> 8;
#pragma unroll
  for (int mt = 0; mt < 4; ++mt)
#pragma unroll
    for (int j = 0; j < 4; ++j) {
      int b = m0 + mt * 16 + quad * 4 + j;
      float s = 0.f;
#pragma unroll
      for (int nt = 0; nt < 4; ++nt) {
        int n = n0 + nt * 16 + fr;
        int d = (nb + nt * 16 + fr) & 255;
        float v = acc[mt][nt][j] + bias[n];
        s += isCr ? v * znr[(size_t)b * 256 + d] : -(v * zni[(size_t)b * 256 + d]);
      }
      s += __shfl_xor(s, 1); s += __shfl_xor(s, 2);
      s += __shfl_xor(s, 4); s += __shfl_xor(s, 8);
      if ((l & 15) == 0) atomicAdd(&ytout[(size_t)b * 50 + nn], s);
    }
}

// ---------------------------------------------------------------- launch
extern "C" void kernel_launch(void* const* d_in, const int* in_sizes, int n_in,
                              void* d_out, int out_size, void* d_ws, size_t ws_size,
                              hipStream_t stream) {
  (void)in_sizes; (void)n_in; (void)out_size; (void)ws_size;
  const float* zt  = (const float*)d_in[0];
  const float* dt  = (const float*)d_in[1];
  const float* ut  = (const float*)d_in[2];
  const float* W0  = (const float*)d_in[3];  const float* b0  = (const float*)d_in[4];
  const float* W1  = (const float*)d_in[5];  const float* b1  = (const float*)d_in[6];
  const float* W2  = (const float*)d_in[7];  const float* b2  = (const float*)d_in[8];
  const float* Wa  = (const float*)d_in[9];  const float* ba  = (const float*)d_in[10];
  const float* Wo  = (const float*)d_in[11]; const float* bo  = (const float*)d_in[12];
  const float* WUr = (const float*)d_in[13]; const float* bUr = (const float*)d_in[14];
  const float* WUi = (const float*)d_in[15]; const float* bUi = (const float*)d_in[16];
  const float* WVr = (const float*)d_in[17]; const float* bVr = (const float*)d_in[18];
  const float* WVi = (const float*)d_in[19]; const float* bVi = (const float*)d_in[20];
  const float* WBr = (const float*)d_in[21]; const float* bBr = (const float*)d_in[22];
  const float* WBi = (const float*)d_in[23]; const float* bBi = (const float*)d_in[24];
  const float* WCr = (const float*)d_in[25]; const float* bCr = (const float*)d_in[26];
  const float* WCi = (const float*)d_in[27]; const float* bCi = (const float*)d_in[28];
  const float* WD  = (const float*)d_in[29]; const float* bD  = (const float*)d_in[30];
  const float* g0  = (const float*)d_in[31]; const float* be0 = (const float*)d_in[32];
  const float* g1  = (const float*)d_in[33]; const float* be1 = (const float*)d_in[34];

  char* ws = (char*)d_ws;
  bf16*  WTbig = (bf16*)(ws + 0);            // [22656, 512] bf16
  bf16*  WTU   = (bf16*)(ws + 23199744);     // [4096, 512]
  bf16*  WTC   = (bf16*)(ws + 27394048);     // [25600, 512]
  bf16*  hz    = (bf16*)(ws + 53608448);     // [2048, 512]
  float* s0    = (float*)(ws + 55705600);    // [2048, 128]
  float* s1    = (float*)(ws + 56754176);    // [2048, 128]
  float* mu0   = (float*)(ws + 57802752);
  float* rstd0 = mu0 + 128;
  float* mu1   = mu0 + 256;
  float* rstd1 = mu0 + 384;
  float* bbigA = (float*)(ws + 57804800);    // [22656]
  float* bbigB = (float*)(ws + 57895424);    // [4096]
  float* bbigC = (float*)(ws + 57911808);    // [25600]
  float* pa    = (float*)(ws + 58014208);    // [2048, 256]
  float* po    = (float*)(ws + 60111360);
  float* Bzr   = (float*)(ws + 62208512);
  float* Bzi   = (float*)(ws + 64305664);
  float* tbuf  = (float*)(ws + 66402816);    // [2048, 8, 2]
  float* lr    = (float*)(ws + 66533888);    // [2048, 256, 2]
  float* znr   = (float*)(ws + 70728192);
  float* zni   = (float*)(ws + 72825344);    // ends 74,922,496
  float* zout  = (float*)d_out;
  float* ytout = zout + 2048 * 512;

  P0Args pa0;
  {
    int tile0 = 0; int idx = 0;
    auto add = [&](const float* src, bf16* dst, int N) {
      int ntn = N >> 6;
      pa0.e[idx].src = src; pa0.e[idx].dst = dst; pa0.e[idx].N = N;
      pa0.e[idx].tile0 = tile0; pa0.e[idx].ntn = ntn;
      tile0 += ntn * 8; ++idx;
    };
    add(Wa,  WTbig + (size_t)0 * 512,     256);
    add(Wo,  WTbig + (size_t)256 * 512,   256);
    add(WVr, WTbig + (size_t)512 * 512,   2048);
    add(WVi, WTbig + (size_t)2560 * 512,  2048);
    add(WBr, WTbig + (size_t)4608 * 512,  8192);
    add(WBi, WTbig + (size_t)12800 * 512, 8192);
    add(WD,  WTbig + (size_t)20992 * 512, 1600);
    add(WUr, WTU,                         2048);
    add(WUi, WTU + (size_t)2048 * 512,    2048);
    add(WCr, WTC,                         12800);
    add(WCi, WTC + (size_t)12800 * 512,   12800);
    // tile0 == 6536
  }
  pa0.ba = ba; pa0.bo = bo; pa0.bVr = bVr; pa0.bVi = bVi; pa0.bBr = bBr;
  pa0.bBi = bBi; pa0.bD = bD; pa0.bUr = bUr; pa0.bUi = bUi; pa0.bCr = bCr;
  pa0.bCi = bCi;
  pa0.bbigA = bbigA; pa0.bbigB = bbigB; pa0.bbigC = bbigC;
  pa0.tbuf = tbuf; pa0.lr = lr;
  pa0.zt = zt; pa0.dt = dt; pa0.ut = ut; pa0.W0 = W0; pa0.b0 = b0; pa0.s0 = s0;

  // 6536 transpose + 205 prep + 1056 zero + 1024 lin0 = 8821 blocks
  k_p0<<<8821, 256, 0, stream>>>(pa0);

  k_stats<<<128, 256, 0, stream>>>(s0, mu0, rstd0);
  k_lin1<<<1024, 256, 0, stream>>>(s0, mu0, rstd0, g0, be0, W1, b1, s1);
  k_stats<<<128, 256, 0, stream>>>(s1, mu1, rstd1);
  k_lin2<<<4096, 256, 0, stream>>>(s1, mu1, rstd1, g1, be1, W2, b2, hz);

  // NT=177 -> pad to 184 n-tiles; invalid tiles early-exit before any barrier.
  k_gemmA<<<184 * 16, 256, 0, stream>>>(hz, WTbig, bbigA, zt, dt, ut,
                                        pa, po, Bzr, Bzi, tbuf, ytout);
  k_gemmB<<<32 * 16, 256, 0, stream>>>(hz, WTU, bbigB, tbuf, lr);
  k_assembleZ<<<2048, 256, 0, stream>>>(zt, pa, po, Bzr, Bzi, lr, zout, znr, zni);
  // gemmC: 400 n-tiles x 32 m-tiles, 64 threads (1 wave) each, barrier-free.
  k_gemmC<<<12800, 64, 0, stream>>>(hz, WTC, bbigC, znr, zni, ytout);
}

// Round 10
// 567.223 us; speedup vs baseline: 1.0659x; 1.0659x over previous
//
#include <hip/hip_runtime.h>
#include <hip/hip_bf16.h>
#include <cstdint>
#include <cstddef>

// S4D-PLR transition model, MI355X (gfx950).
// R11b (second resubmit; __sincosf -> __sinf/__cosf as defensive tweak):
// propagate R9's only-positive A/B (2-buffer core + __launch_bounds__(256,4):
// caps regs at 128/wave incl. 64 AGPR acc -> 4 blocks/CU resident, occupancy
// 29->37.5%, gemmC 120->115) to gemmA and gemmB. gemmC unchanged from R9.
// assembleZ: fast transcendentals (__expf/__logf/__sinf/__cosf); error
// ~1e-6 << 0.039 tolerance.

typedef __bf16 bf16;
typedef __bf16 bf16x8 __attribute__((ext_vector_type(8)));
typedef __bf16 bf16x4 __attribute__((ext_vector_type(4)));
typedef float f32x4 __attribute__((ext_vector_type(4)));

// ---------------------------------------------------------------- async copy
__device__ __forceinline__ void async16(const void* g, void* l) {
  __builtin_amdgcn_global_load_lds((const __attribute__((address_space(1))) void*)g,
                                   (__attribute__((address_space(3))) void*)l, 16, 0, 0);
}

// ---------------------------------------------------------------- tile map
// XCD-aware: blocks L%8 -> XCD; consecutive s=L/8 on one XCD sweep all 16
// m-tiles of one n-tile (B-tile stays in that XCD's L2).
__device__ __forceinline__ bool tile_map(int NT, int& m0, int& n0) {
  int L = blockIdx.x;
  int x = L & 7, s = L >> 3;
  int nt = ((s >> 4) << 3) + x;
  if (nt >= NT) return false;
  n0 = nt << 7;
  m0 = (s & 15) << 7;
  return true;
}

// ---------------------------------------------------------------- GEMM core
// C[128x128] = A[128x512] * Bw^T (Bw [N,512] bf16, k-contiguous).
// 4 waves (2x2), each 64x64 via 4x4 mfma_f32_16x16x32_bf16.
// LDS: 2 buffers, buf p at lds+p*8192 elems; A-tile (128x32) at +0,
// B-tile at +4096. Chunk c (=tid, tid+256) holds row c>>2, swizzled k-chunk
// (c&3)^((row>>1)&3) (bank swizzle on the global-address side; verified
// conflict-free, SQ_LDS_BANK_CONFLICT=0). Per iter: vmcnt(0) -> s_barrier ->
// issue(next, p^1) -> ds_read(cur) -> MFMA (counted lgkm) -> lgkmcnt(0).
// WAR-safe: p^1 was read at step it-1 and lgkm-drained before barrier(it).
__device__ __forceinline__ void gemm_p2(const bf16* __restrict__ A,
                                        const bf16* __restrict__ Bw,
                                        int m0, int n0,
                                        bf16* lds, f32x4 acc[4][4]) {
  const int tid = threadIdx.x;
  const int w = tid >> 6, l = tid & 63;
  const int wm = (w >> 1) << 6, wn = (w & 1) << 6;
  const int fr = l & 15, q = l >> 4;

  const int c0 = tid, c1 = tid + 256;
  const int r0 = c0 >> 2, k0 = ((c0 & 3) ^ ((r0 >> 1) & 3)) << 3;
  const int r1 = c1 >> 2, k1 = ((c1 & 3) ^ ((r1 >> 1) & 3)) << 3;
  const bf16* a0 = A + (size_t)(m0 + r0) * 512 + k0;
  const bf16* a1 = A + (size_t)(m0 + r1) * 512 + k1;
  const bf16* b0 = Bw + (size_t)(n0 + r0) * 512 + k0;
  const bf16* b1 = Bw + (size_t)(n0 + r1) * 512 + k1;
  const int sw = (q ^ ((fr >> 1) & 3)) << 3;             // reader un-swizzle

#pragma unroll
  for (int mt = 0; mt < 4; ++mt)
#pragma unroll
    for (int nt = 0; nt < 4; ++nt) { f32x4 z = {0.f, 0.f, 0.f, 0.f}; acc[mt][nt] = z; }

  auto issue = [&](int kt, int p) {
    bf16* d = lds + p * 8192;
    async16(a0 + kt, d + (c0 << 3));
    async16(a1 + kt, d + (c1 << 3));
    async16(b0 + kt, d + 4096 + (c0 << 3));
    async16(b1 + kt, d + 4096 + (c1 << 3));
  };

  issue(0, 0);
#pragma unroll
  for (int it = 0; it < 16; ++it) {
    const int p = it & 1;
    asm volatile("s_waitcnt vmcnt(0)" ::: "memory");      // buf it landed
    asm volatile("s_barrier" ::: "memory");                // all waves see it
    if (it + 1 < 16) issue((it + 1) << 5, p ^ 1);         // WAR-safe post-barrier
    const bf16* ab = lds + p * 8192;
    const bf16* bb = ab + 4096;
    bf16x8 af[4], bfv[4];
#pragma unroll
    for (int mt = 0; mt < 4; ++mt)
      af[mt] = *(const bf16x8*)(ab + (wm + mt * 16 + fr) * 32 + sw);
#pragma unroll
    for (int nt = 0; nt < 4; ++nt)
      bfv[nt] = *(const bf16x8*)(bb + (wn + nt * 16 + fr) * 32 + sw);
#pragma unroll
    for (int mt = 0; mt < 4; ++mt)
#pragma unroll
      for (int nt = 0; nt < 4; ++nt)
        acc[mt][nt] = __builtin_amdgcn_mfma_f32_16x16x32_bf16(af[mt], bfv[nt],
                                                              acc[mt][nt], 0, 0, 0);
    asm volatile("s_waitcnt lgkmcnt(0)" ::: "memory");   // my reads done pre-barrier
  }
}
// C/D layout (verified m89/m91): col = lane&15, row = (lane>>4)*4 + reg.

// ---------------------------------------------------------------- fused phase-0
// Block ranges: [0,6536) transpose | [6536,6741) bias gather |
// [6741,7797) zero tbuf+lr | [7797,8821) lin0.
struct TEntry { const float* src; bf16* dst; int N, tile0, ntn; };
struct P0Args {
  TEntry e[11];
  const float *ba, *bo, *bVr, *bVi, *bBr, *bBi, *bD, *bUr, *bUi, *bCr, *bCi;
  float *bbigA, *bbigB, *bbigC;
  float *tbuf, *lr;
  const float *zt, *dt, *ut, *W0, *b0;
  float* s0;
};

__global__ void k_p0(P0Args a) {
  __shared__ float tile[64][65];
  const int blk = blockIdx.x;
  const int tid = threadIdx.x;

  if (blk < 6536) {                                   // ---- weight transpose
    int t = blk;
    int ei = 0;
    while (ei < 10 && t >= a.e[ei + 1].tile0) ++ei;
    const TEntry E = a.e[ei];
    int lt = t - E.tile0;
    int tk = lt / E.ntn, tn = lt - tk * E.ntn;
    int k0 = tk << 6, n0 = tn << 6;
#pragma unroll
    for (int i = 0; i < 4; ++i) {
      int idx = tid + i * 256;
      int kk = idx >> 4, c4 = (idx & 15) << 2;
      const float4 v = *(const float4*)(E.src + (size_t)(k0 + kk) * E.N + n0 + c4);
      tile[c4 + 0][kk] = v.x; tile[c4 + 1][kk] = v.y;
      tile[c4 + 2][kk] = v.z; tile[c4 + 3][kk] = v.w;
    }
    __syncthreads();
#pragma unroll
    for (int i = 0; i < 4; ++i) {
      int idx = tid + i * 256;
      int nn = idx >> 4, k4 = (idx & 15) << 2;
      bf16x4 o;
      o[0] = (bf16)tile[nn][k4 + 0]; o[1] = (bf16)tile[nn][k4 + 1];
      o[2] = (bf16)tile[nn][k4 + 2]; o[3] = (bf16)tile[nn][k4 + 3];
      *(bf16x4*)(E.dst + (size_t)(n0 + nn) * 512 + k0 + k4) = o;
    }
  } else if (blk < 6741) {                            // ---- bias gather
    int i = (blk - 6536) * 256 + tid;
    if (i < 22656) {
      float v;
      if (i < 256) v = a.ba[i];
      else if (i < 512) v = a.bo[i - 256];
      else if (i < 2560) v = a.bVr[i - 512];
      else if (i < 4608) v = a.bVi[i - 2560];
      else if (i < 12800) v = a.bBr[i - 4608];
      else if (i < 20992) v = a.bBi[i - 12800];
      else if (i < 22592) v = a.bD[i - 20992];
      else v = 0.f;
      a.bbigA[i] = v;
    }
    int j = i - 22656;
    if (j >= 0 && j < 4096) a.bbigB[j] = (j < 2048) ? a.bUr[j] : a.bUi[j - 2048];
    int m = i - (22656 + 4096);
    if (m >= 0 && m < 25600) a.bbigC[m] = (m < 12800) ? a.bCr[m] : a.bCi[m - 12800];
  } else if (blk < 7797) {                            // ---- zero tbuf (8192 f4) + lr
    int idx = (blk - 6741) * 256 + tid;
    float4 z = {0.f, 0.f, 0.f, 0.f};
    if (idx < 8192) *(float4*)(a.tbuf + idx * 4) = z;
    else            *(float4*)(a.lr + (idx - 8192) * 4) = z;   // 262144 f4
  } else {                                            // ---- lin0 (selector layer 0)
    int i = (blk - 7797) * 256 + tid;                 // 2048*128
    int b = i >> 7, c = i & 127;
    const float* w = a.W0 + c;
    const float* x = a.zt + (size_t)b * 512;
    float a0 = a.b0[c], a1 = 0.f, a2 = 0.f, a3 = 0.f;
#pragma unroll 4
    for (int k = 0; k < 512; k += 4) {
      a0 = fmaf(x[k + 0], w[(size_t)(k + 0) * 128], a0);
      a1 = fmaf(x[k + 1], w[(size_t)(k + 1) * 128], a1);
      a2 = fmaf(x[k + 2], w[(size_t)(k + 2) * 128], a2);
      a3 = fmaf(x[k + 3], w[(size_t)(k + 3) * 128], a3);
    }
    const float* u = a.ut + (size_t)b * 32;
#pragma unroll
    for (int k = 0; k < 32; k += 4) {
      a0 = fmaf(u[k + 0], w[(size_t)(512 + k + 0) * 128], a0);
      a1 = fmaf(u[k + 1], w[(size_t)(512 + k + 1) * 128], a1);
      a2 = fmaf(u[k + 2], w[(size_t)(512 + k + 2) * 128], a2);
      a3 = fmaf(u[k + 3], w[(size_t)(512 + k + 3) * 128], a3);
    }
    a0 = fmaf(a.dt[b], w[(size_t)544 * 128], a0);
    a.s0[i] = (a0 + a1) + (a2 + a3);
  }
}

// ---------------------------------------------------------------- BN stats
__global__ void k_stats(const float* __restrict__ s, float* __restrict__ mu,
                        float* __restrict__ rstd) {
  int c = blockIdx.x;                           // 128 columns
  float sm = 0.f, sq = 0.f;
  for (int r = threadIdx.x; r < 2048; r += 256) {
    float v = s[(size_t)r * 128 + c];
    sm += v; sq += v * v;
  }
#pragma unroll
  for (int o = 32; o >= 1; o >>= 1) { sm += __shfl_down(sm, o); sq += __shfl_down(sq, o); }
  __shared__ float red[8];
  int w = threadIdx.x >> 6;
  if ((threadIdx.x & 63) == 0) { red[w] = sm; red[4 + w] = sq; }
  __syncthreads();
  if (threadIdx.x == 0) {
    float S = red[0] + red[1] + red[2] + red[3];
    float Q = red[4] + red[5] + red[6] + red[7];
    float m = S * (1.f / 2048.f);
    float var = Q * (1.f / 2048.f) - m * m;    // biased var (training-mode BN)
    mu[c] = m;
    rstd[c] = rsqrtf(var + 1e-5f);
  }
}

// ---------------------------------------------------------------- lin1/lin2 (inline BN)
__global__ void k_lin1(const float* __restrict__ s0, const float* __restrict__ mu,
                       const float* __restrict__ rstd, const float* __restrict__ g,
                       const float* __restrict__ be, const float* __restrict__ W1,
                       const float* __restrict__ b1, float* __restrict__ s1) {
  int i = blockIdx.x * 256 + threadIdx.x;      // 2048*128
  int b = i >> 7, c = i & 127;
  const float* w = W1 + c;
  const float* x = s0 + (size_t)b * 128;
  float a0 = b1[c], a1 = 0.f, a2 = 0.f, a3 = 0.f;
#pragma unroll 4
  for (int k = 0; k < 128; k += 4) {
    float h0 = fmaxf(fmaf((x[k + 0] - mu[k + 0]) * rstd[k + 0], g[k + 0], be[k + 0]), 0.f);
    float h1 = fmaxf(fmaf((x[k + 1] - mu[k + 1]) * rstd[k + 1], g[k + 1], be[k + 1]), 0.f);
    float h2 = fmaxf(fmaf((x[k + 2] - mu[k + 2]) * rstd[k + 2], g[k + 2], be[k + 2]), 0.f);
    float h3 = fmaxf(fmaf((x[k + 3] - mu[k + 3]) * rstd[k + 3], g[k + 3], be[k + 3]), 0.f);
    a0 = fmaf(h0, w[(size_t)(k + 0) * 128], a0);
    a1 = fmaf(h1, w[(size_t)(k + 1) * 128], a1);
    a2 = fmaf(h2, w[(size_t)(k + 2) * 128], a2);
    a3 = fmaf(h3, w[(size_t)(k + 3) * 128], a3);
  }
  s1[i] = (a0 + a1) + (a2 + a3);
}

__global__ void k_lin2(const float* __restrict__ s1, const float* __restrict__ mu,
                       const float* __restrict__ rstd, const float* __restrict__ g,
                       const float* __restrict__ be, const float* __restrict__ W2,
                       const float* __restrict__ b2, bf16* __restrict__ hz) {
  int i = blockIdx.x * 256 + threadIdx.x;      // 2048*512
  int b = i >> 9, c = i & 511;
  const float* w = W2 + c;
  const float* x = s1 + (size_t)b * 128;
  float a0 = b2[c], a1 = 0.f, a2 = 0.f, a3 = 0.f;
#pragma unroll 4
  for (int k = 0; k < 128; k += 4) {
    float h0 = fmaxf(fmaf((x[k + 0] - mu[k + 0]) * rstd[k + 0], g[k + 0], be[k + 0]), 0.f);
    float h1 = fmaxf(fmaf((x[k + 1] - mu[k + 1]) * rstd[k + 1], g[k + 1], be[k + 1]), 0.f);
    float h2 = fmaxf(fmaf((x[k + 2] - mu[k + 2]) * rstd[k + 2], g[k + 2], be[k + 2]), 0.f);
    float h3 = fmaxf(fmaf((x[k + 3] - mu[k + 3]) * rstd[k + 3], g[k + 3], be[k + 3]), 0.f);
    a0 = fmaf(h0, w[(size_t)(k + 0) * 512], a0);
    a1 = fmaf(h1, w[(size_t)(k + 1) * 512], a1);
    a2 = fmaf(h2, w[(size_t)(k + 2) * 512], a2);
    a3 = fmaf(h3, w[(size_t)(k + 3) * 512], a3);
  }
  hz[i] = (bf16)((a0 + a1) + (a2 + a3));
}

// ---------------------------------------------------------------- phase A GEMM
// columns: [0,256) a | [256,512) o | [512,2560) Vr | [2560,4608) Vi
//          [4608,12800) Br | [12800,20992) Bi | [20992,22592) D | pad to 22656
__global__ __launch_bounds__(256, 4) void k_gemmA(
    const bf16* __restrict__ hz, const bf16* __restrict__ WT, const float* __restrict__ bias,
    const float* __restrict__ zt, const float* __restrict__ dt, const float* __restrict__ ut,
    float* __restrict__ pa, float* __restrict__ po,
    float* __restrict__ Bzr, float* __restrict__ Bzi,
    float* __restrict__ tbuf, float* __restrict__ ytout) {
  int m0, n0;
  if (!tile_map(177, m0, n0)) return;
  __shared__ __align__(16) bf16 lds[16384];
  f32x4 acc[4][4];
  gemm_p2(hz, WT, m0, n0, lds, acc);
  const int l = threadIdx.x & 63, w = threadIdx.x >> 6;
  const int wm = (w >> 1) << 6, wn = (w & 1) << 6;
  const int fr = l & 15, quad = l >> 4;
  const int ncol = n0 + wn;

  if (n0 < 512) {                                    // ---- a / o pre-acts
    float* dst = (n0 < 256) ? pa : po;
    int cb = ncol - ((n0 < 256) ? 0 : 256);
#pragma unroll
    for (int mt = 0; mt < 4; ++mt)
#pragma unroll
      for (int j = 0; j < 4; ++j) {
        int b = m0 + wm + mt * 16 + quad * 4 + j;
#pragma unroll
        for (int nt = 0; nt < 4; ++nt) {
          int n = ncol + nt * 16 + fr;
          dst[(size_t)b * 256 + (cb + nt * 16 + fr)] = acc[mt][nt][j] + bias[n];
        }
      }
  } else if (n0 < 4608) {                            // ---- V: t = conj(V)^T z
    const bool isVr = n0 < 2560;
#pragma unroll
    for (int mt = 0; mt < 4; ++mt)
#pragma unroll
      for (int j = 0; j < 4; ++j) {
        int b = m0 + wm + mt * 16 + quad * 4 + j;
        float cre = 0.f, cim = 0.f;
#pragma unroll
        for (int nt = 0; nt < 4; ++nt) {
          int n = ncol + nt * 16 + fr;
          float v = acc[mt][nt][j] + bias[n];
          int d = ((n - 512) & 2047) >> 3;
          float zr = zt[(size_t)b * 512 + d], zi = zt[(size_t)b * 512 + 256 + d];
          if (isVr) { cre += v * zr; cim += v * zi; }
          else      { cre += v * zi; cim -= v * zr; }
        }
        cre += __shfl_xor(cre, 8);
        cim += __shfl_xor(cim, 8);
        if ((l & 8) == 0) {
          int r = fr & 7;
          atomicAdd(&tbuf[((size_t)b * 8 + r) * 2 + 0], cre);
          atomicAdd(&tbuf[((size_t)b * 8 + r) * 2 + 1], cim);
        }
      }
  } else if (n0 < 20992) {                           // ---- B: Bz = Bt @ (ut*dt)
    const bool isBr = n0 < 12800;
    float* dst = isBr ? Bzr : Bzi;
#pragma unroll
    for (int mt = 0; mt < 4; ++mt)
#pragma unroll
      for (int j = 0; j < 4; ++j) {
        int b = m0 + wm + mt * 16 + quad * 4 + j;
        float dtb = dt[b];
#pragma unroll
        for (int g = 0; g < 2; ++g) {
          float s = 0.f;
#pragma unroll
          for (int h = 0; h < 2; ++h) {
            int nt = g * 2 + h;
            int n = ncol + nt * 16 + fr;
            int base = (n - 4608) & 8191;
            float v = acc[mt][nt][j] + bias[n];
            s += v * ut[(size_t)b * 32 + (base & 31)];
          }
          s *= dtb;
          s += __shfl_xor(s, 1); s += __shfl_xor(s, 2);
          s += __shfl_xor(s, 4); s += __shfl_xor(s, 8);
          if ((l & 15) == 0) {
            int d = (((ncol + g * 32) - 4608) & 8191) >> 5;
            dst[(size_t)b * 256 + d] = s;
          }
        }
      }
  } else {                                           // ---- D: yt init
#pragma unroll
    for (int mt = 0; mt < 4; ++mt)
#pragma unroll
      for (int j = 0; j < 4; ++j) {
        int b = m0 + wm + mt * 16 + quad * 4 + j;
        float dtb = dt[b];
#pragma unroll
        for (int g = 0; g < 2; ++g) {
          float s = 0.f;
#pragma unroll
          for (int h = 0; h < 2; ++h) {
            int nt = g * 2 + h;
            int n = ncol + nt * 16 + fr;
            int base = n - 20992;
            float v = acc[mt][nt][j] + bias[n];
            s += v * ut[(size_t)b * 32 + (base & 31)];
          }
          s *= dtb;
          s += __shfl_xor(s, 1); s += __shfl_xor(s, 2);
          s += __shfl_xor(s, 4); s += __shfl_xor(s, 8);
          int nn = ((ncol + g * 32) - 20992) >> 5;
          if ((l & 15) == 0 && nn < 50) ytout[(size_t)b * 50 + nn] = s;
        }
      }
  }
}

// ---------------------------------------------------------------- phase B GEMM (U)
__global__ __launch_bounds__(256, 4) void k_gemmB(
    const bf16* __restrict__ hz, const bf16* __restrict__ WT, const float* __restrict__ bias,
    const float* __restrict__ tbuf, float* __restrict__ lr) {
  int m0, n0;
  if (!tile_map(32, m0, n0)) return;
  __shared__ __align__(16) bf16 lds[16384];
  f32x4 acc[4][4];
  gemm_p2(hz, WT, m0, n0, lds, acc);
  const int l = threadIdx.x & 63, w = threadIdx.x >> 6;
  const int wm = (w >> 1) << 6, wn = (w & 1) << 6;
  const int fr = l & 15, quad = l >> 4;
  const int ncol = n0 + wn;
  const bool isUr = n0 < 2048;
#pragma unroll
  for (int mt = 0; mt < 4; ++mt)
#pragma unroll
    for (int j = 0; j < 4; ++j) {
      int b = m0 + wm + mt * 16 + quad * 4 + j;
#pragma unroll
      for (int nt = 0; nt < 4; ++nt) {
        int n = ncol + nt * 16 + fr;
        int base = n & 2047;
        int r = base & 7, d = base >> 3;
        float v = acc[mt][nt][j] + bias[n];
        float tre = tbuf[((size_t)b * 8 + r) * 2], tim = tbuf[((size_t)b * 8 + r) * 2 + 1];
        float cre = isUr ? v * tre : -v * tim;
        float cim = isUr ? v * tim :  v * tre;
        cre += __shfl_xor(cre, 1); cre += __shfl_xor(cre, 2); cre += __shfl_xor(cre, 4);
        cim += __shfl_xor(cim, 1); cim += __shfl_xor(cim, 2); cim += __shfl_xor(cim, 4);
        if ((l & 7) == 0) {
          atomicAdd(&lr[((size_t)b * 256 + d) * 2 + 0], cre);
          atomicAdd(&lr[((size_t)b * 256 + d) * 2 + 1], cim);
        }
      }
    }
}

// ---------------------------------------------------------------- z_next assembly
__global__ void k_assembleZ(const float* __restrict__ zt, const float* __restrict__ pa,
                            const float* __restrict__ po, const float* __restrict__ Bzr,
                            const float* __restrict__ Bzi, const float* __restrict__ lr,
                            float* __restrict__ zout, float* __restrict__ znr,
                            float* __restrict__ zni) {
  int i = blockIdx.x * 256 + threadIdx.x;      // 2048*256
  int b = i >> 8, d = i & 255;
  float a = pa[i], o = po[i];
  float e = __expf(-fabsf(a));
  float sp = fmaxf(a, 0.f) + __logf(1.f + e);   // softplus, stable (fast path)
  float mag = __expf(-sp);
  float sn = __sinf(o), cs = __cosf(o);
  float Lr = mag * cs, Li = mag * sn;
  float zr = zt[(size_t)b * 512 + d], zi = zt[(size_t)b * 512 + 256 + d];
  float re = fmaf(Lr, zr, -Li * zi) + Bzr[i] + lr[2 * i];
  float im = fmaf(Lr, zi,  Li * zr) + Bzi[i] + lr[2 * i + 1];
  zout[(size_t)b * 512 + d] = re;
  zout[(size_t)b * 512 + 256 + d] = im;
  znr[i] = re; zni[i] = im;
}

// ---------------------------------------------------------------- phase C GEMM (C)
__global__ __launch_bounds__(256, 4) void k_gemmC(
    const bf16* __restrict__ hz, const bf16* __restrict__ WT, const float* __restrict__ bias,
    const float* __restrict__ znr, const float* __restrict__ zni, float* __restrict__ ytout) {
  int m0, n0;
  if (!tile_map(200, m0, n0)) return;
  __shared__ __align__(16) bf16 lds[16384];
  f32x4 acc[4][4];
  gemm_p2(hz, WT, m0, n0, lds, acc);
  const int l = threadIdx.x & 63, w = threadIdx.x >> 6;
  const int wm = (w >> 1) << 6, wn = (w & 1) << 6;
  const int fr = l & 15, quad = l >> 4;
  const int ncol = n0 + wn;
  const bool isCr = n0 < 12800;
  const int nb = ncol - (isCr ? 0 : 12800);
  const int nn = nb >> 8;
#pragma unroll
  for (int mt = 0; mt < 4; ++mt)
#pragma unroll
    for (int j = 0; j < 4; ++j) {
      int b = m0 + wm + mt * 16 + quad * 4 + j;
      float s = 0.f;
#pragma unroll
      for (int nt = 0; nt < 4; ++nt) {
        int n = ncol + nt * 16 + fr;
        int d = (nb + nt * 16 + fr) & 255;
        float v = acc[mt][nt][j] + bias[n];
        s += isCr ? v * znr[(size_t)b * 256 + d] : -(v * zni[(size_t)b * 256 + d]);
      }
      s += __shfl_xor(s, 1); s += __shfl_xor(s, 2);
      s += __shfl_xor(s, 4); s += __shfl_xor(s, 8);
      if ((l & 15) == 0) atomicAdd(&ytout[(size_t)b * 50 + nn], s);
    }
}

// ---------------------------------------------------------------- launch
extern "C" void kernel_launch(void* const* d_in, const int* in_sizes, int n_in,
                              void* d_out, int out_size, void* d_ws, size_t ws_size,
                              hipStream_t stream) {
  (void)in_sizes; (void)n_in; (void)out_size; (void)ws_size;
  const float* zt  = (const float*)d_in[0];
  const float* dt  = (const float*)d_in[1];
  const float* ut  = (const float*)d_in[2];
  const float* W0  = (const float*)d_in[3];  const float* b0  = (const float*)d_in[4];
  const float* W1  = (const float*)d_in[5];  const float* b1  = (const float*)d_in[6];
  const float* W2  = (const float*)d_in[7];  const float* b2  = (const float*)d_in[8];
  const float* Wa  = (const float*)d_in[9];  const float* ba  = (const float*)d_in[10];
  const float* Wo  = (const float*)d_in[11]; const float* bo  = (const float*)d_in[12];
  const float* WUr = (const float*)d_in[13]; const float* bUr = (const float*)d_in[14];
  const float* WUi = (const float*)d_in[15]; const float* bUi = (const float*)d_in[16];
  const float* WVr = (const float*)d_in[17]; const float* bVr = (const float*)d_in[18];
  const float* WVi = (const float*)d_in[19]; const float* bVi = (const float*)d_in[20];
  const float* WBr = (const float*)d_in[21]; const float* bBr = (const float*)d_in[22];
  const float* WBi = (const float*)d_in[23]; const float* bBi = (const float*)d_in[24];
  const float* WCr = (const float*)d_in[25]; const float* bCr = (const float*)d_in[26];
  const float* WCi = (const float*)d_in[27]; const float* bCi = (const float*)d_in[28];
  const float* WD  = (const float*)d_in[29]; const float* bD  = (const float*)d_in[30];
  const float* g0  = (const float*)d_in[31]; const float* be0 = (const float*)d_in[32];
  const float* g1  = (const float*)d_in[33]; const float* be1 = (const float*)d_in[34];

  char* ws = (char*)d_ws;
  bf16*  WTbig = (bf16*)(ws + 0);            // [22656, 512] bf16
  bf16*  WTU   = (bf16*)(ws + 23199744);     // [4096, 512]
  bf16*  WTC   = (bf16*)(ws + 27394048);     // [25600, 512]
  bf16*  hz    = (bf16*)(ws + 53608448);     // [2048, 512]
  float* s0    = (float*)(ws + 55705600);    // [2048, 128]
  float* s1    = (float*)(ws + 56754176);    // [2048, 128]
  float* mu0   = (float*)(ws + 57802752);
  float* rstd0 = mu0 + 128;
  float* mu1   = mu0 + 256;
  float* rstd1 = mu0 + 384;
  float* bbigA = (float*)(ws + 57804800);    // [22656]
  float* bbigB = (float*)(ws + 57895424);    // [4096]
  float* bbigC = (float*)(ws + 57911808);    // [25600]
  float* pa    = (float*)(ws + 58014208);    // [2048, 256]
  float* po    = (float*)(ws + 60111360);
  float* Bzr   = (float*)(ws + 62208512);
  float* Bzi   = (float*)(ws + 64305664);
  float* tbuf  = (float*)(ws + 66402816);    // [2048, 8, 2]
  float* lr    = (float*)(ws + 66533888);    // [2048, 256, 2]
  float* znr   = (float*)(ws + 70728192);
  float* zni   = (float*)(ws + 72825344);    // ends 74,922,496
  float* zout  = (float*)d_out;
  float* ytout = zout + 2048 * 512;

  P0Args pa0;
  {
    int tile0 = 0; int idx = 0;
    auto add = [&](const float* src, bf16* dst, int N) {
      int ntn = N >> 6;
      pa0.e[idx].src = src; pa0.e[idx].dst = dst; pa0.e[idx].N = N;
      pa0.e[idx].tile0 = tile0; pa0.e[idx].ntn = ntn;
      tile0 += ntn * 8; ++idx;
    };
    add(Wa,  WTbig + (size_t)0 * 512,     256);
    add(Wo,  WTbig + (size_t)256 * 512,   256);
    add(WVr, WTbig + (size_t)512 * 512,   2048);
    add(WVi, WTbig + (size_t)2560 * 512,  2048);
    add(WBr, WTbig + (size_t)4608 * 512,  8192);
    add(WBi, WTbig + (size_t)12800 * 512, 8192);
    add(WD,  WTbig + (size_t)20992 * 512, 1600);
    add(WUr, WTU,                         2048);
    add(WUi, WTU + (size_t)2048 * 512,    2048);
    add(WCr, WTC,                         12800);
    add(WCi, WTC + (size_t)12800 * 512,   12800);
    // tile0 == 6536
  }
  pa0.ba = ba; pa0.bo = bo; pa0.bVr = bVr; pa0.bVi = bVi; pa0.bBr = bBr;
  pa0.bBi = bBi; pa0.bD = bD; pa0.bUr = bUr; pa0.bUi = bUi; pa0.bCr = bCr;
  pa0.bCi = bCi;
  pa0.bbigA = bbigA; pa0.bbigB = bbigB; pa0.bbigC = bbigC;
  pa0.tbuf = tbuf; pa0.lr = lr;
  pa0.zt = zt; pa0.dt = dt; pa0.ut = ut; pa0.W0 = W0; pa0.b0 = b0; pa0.s0 = s0;

  // 6536 transpose + 205 prep + 1056 zero + 1024 lin0 = 8821 blocks
  k_p0<<<8821, 256, 0, stream>>>(pa0);

  k_stats<<<128, 256, 0, stream>>>(s0, mu0, rstd0);
  k_lin1<<<1024, 256, 0, stream>>>(s0, mu0, rstd0, g0, be0, W1, b1, s1);
  k_stats<<<128, 256, 0, stream>>>(s1, mu1, rstd1);
  k_lin2<<<4096, 256, 0, stream>>>(s1, mu1, rstd1, g1, be1, W2, b2, hz);

  // NT=177 -> pad to 184 n-tiles; invalid tiles early-exit before any barrier.
  k_gemmA<<<184 * 16, 256, 0, stream>>>(hz, WTbig, bbigA, zt, dt, ut,
                                        pa, po, Bzr, Bzi, tbuf, ytout);
  k_gemmB<<<32 * 16, 256, 0, stream>>>(hz, WTU, bbigB, tbuf, lr);
  k_assembleZ<<<2048, 256, 0, stream>>>(zt, pa, po, Bzr, Bzi, lr, zout, znr, zni);
  k_gemmC<<<200 * 16, 256, 0, stream>>>(hz, WTC, bbigC, znr, zni, ytout);
}

// Round 11
// 559.715 us; speedup vs baseline: 1.0802x; 1.0134x over previous
//
#include <hip/hip_runtime.h>
#include <hip/hip_bf16.h>
#include <cstdint>
#include <cstddef>

// S4D-PLR transition model, MI355X (gfx950).
// R12: consolidation of per-kernel best-measured variants.
// - gemmA/gemmB: gemm_p3 (3-buf, depth-2 prefetch, vmcnt(4), uncapped) —
//   R9's 561us config; R11b showed the (256,4)+2buf cap HURTS heavy-epilogue
//   kernels (gemmA +6us: 64-VGPR cap serializes the V/B/D epilogue).
// - gemmC: gemm_p2 + __launch_bounds__(256,4) — reproducibly 113.5-115us
//   (best of 5 structural variants; 4 blocks/CU, VGPR=64, no spill).
// - p0 fusion, inline-BN lin1/lin2, fast transcendentals in assembleZ.

typedef __bf16 bf16;
typedef __bf16 bf16x8 __attribute__((ext_vector_type(8)));
typedef __bf16 bf16x4 __attribute__((ext_vector_type(4)));
typedef float f32x4 __attribute__((ext_vector_type(4)));

// ---------------------------------------------------------------- async copy
__device__ __forceinline__ void async16(const void* g, void* l) {
  __builtin_amdgcn_global_load_lds((const __attribute__((address_space(1))) void*)g,
                                   (__attribute__((address_space(3))) void*)l, 16, 0, 0);
}

// ---------------------------------------------------------------- tile map
// XCD-aware: blocks L%8 -> XCD; consecutive s=L/8 on one XCD sweep all 16
// m-tiles of one n-tile (B-tile stays in that XCD's L2).
__device__ __forceinline__ bool tile_map(int NT, int& m0, int& n0) {
  int L = blockIdx.x;
  int x = L & 7, s = L >> 3;
  int nt = ((s >> 4) << 3) + x;
  if (nt >= NT) return false;
  n0 = nt << 7;
  m0 = (s & 15) << 7;
  return true;
}

// ---------------------------------------------------------------- GEMM cores
// C[128x128] = A[128x512] * Bw^T (Bw [N,512] bf16, k-contiguous).
// 4 waves (2x2), each 64x64 via 4x4 mfma_f32_16x16x32_bf16.
// Chunk c (=tid, tid+256) holds row c>>2, swizzled k-chunk (c&3)^((row>>1)&3)
// (bank swizzle on the global-address side; verified conflict-free).

// 3-buffer, depth-2, vmcnt(4) pacing (best for heavy-epilogue kernels).
__device__ __forceinline__ void gemm_p3(const bf16* __restrict__ A,
                                        const bf16* __restrict__ Bw,
                                        int m0, int n0,
                                        bf16* lds, f32x4 acc[4][4]) {
  const int tid = threadIdx.x;
  const int w = tid >> 6, l = tid & 63;
  const int wm = (w >> 1) << 6, wn = (w & 1) << 6;
  const int fr = l & 15, q = l >> 4;

  const int c0 = tid, c1 = tid + 256;
  const int r0 = c0 >> 2, k0 = ((c0 & 3) ^ ((r0 >> 1) & 3)) << 3;
  const int r1 = c1 >> 2, k1 = ((c1 & 3) ^ ((r1 >> 1) & 3)) << 3;
  const bf16* a0 = A + (size_t)(m0 + r0) * 512 + k0;
  const bf16* a1 = A + (size_t)(m0 + r1) * 512 + k1;
  const bf16* b0 = Bw + (size_t)(n0 + r0) * 512 + k0;
  const bf16* b1 = Bw + (size_t)(n0 + r1) * 512 + k1;
  const int sw = (q ^ ((fr >> 1) & 3)) << 3;

#pragma unroll
  for (int mt = 0; mt < 4; ++mt)
#pragma unroll
    for (int nt = 0; nt < 4; ++nt) { f32x4 z = {0.f, 0.f, 0.f, 0.f}; acc[mt][nt] = z; }

  auto issue = [&](int kt, int p) {
    bf16* d = lds + p * 8192;
    async16(a0 + kt, d + (c0 << 3));
    async16(a1 + kt, d + (c1 << 3));
    async16(b0 + kt, d + 4096 + (c0 << 3));
    async16(b1 + kt, d + 4096 + (c1 << 3));
  };

  issue(0, 0);
  issue(32, 1);
#pragma unroll
  for (int it = 0; it < 16; ++it) {
    const int p = it % 3;
    if (it < 14) asm volatile("s_waitcnt vmcnt(4)" ::: "memory");  // buf it landed
    else         asm volatile("s_waitcnt vmcnt(0)" ::: "memory");
    asm volatile("s_barrier" ::: "memory");
    if (it + 2 < 16) issue((it + 2) << 5, (it + 2) % 3);  // WAR-safe post-barrier
    const bf16* ab = lds + p * 8192;
    const bf16* bb = ab + 4096;
    bf16x8 af[4], bfv[4];
#pragma unroll
    for (int mt = 0; mt < 4; ++mt)
      af[mt] = *(const bf16x8*)(ab + (wm + mt * 16 + fr) * 32 + sw);
#pragma unroll
    for (int nt = 0; nt < 4; ++nt)
      bfv[nt] = *(const bf16x8*)(bb + (wn + nt * 16 + fr) * 32 + sw);
#pragma unroll
    for (int mt = 0; mt < 4; ++mt)
#pragma unroll
      for (int nt = 0; nt < 4; ++nt)
        acc[mt][nt] = __builtin_amdgcn_mfma_f32_16x16x32_bf16(af[mt], bfv[nt],
                                                              acc[mt][nt], 0, 0, 0);
    asm volatile("s_waitcnt lgkmcnt(0)" ::: "memory");   // reads done pre-barrier
  }
}

// 2-buffer, depth-1, vmcnt(0) pacing (with launch_bounds(256,4): 4 blocks/CU).
__device__ __forceinline__ void gemm_p2(const bf16* __restrict__ A,
                                        const bf16* __restrict__ Bw,
                                        int m0, int n0,
                                        bf16* lds, f32x4 acc[4][4]) {
  const int tid = threadIdx.x;
  const int w = tid >> 6, l = tid & 63;
  const int wm = (w >> 1) << 6, wn = (w & 1) << 6;
  const int fr = l & 15, q = l >> 4;

  const int c0 = tid, c1 = tid + 256;
  const int r0 = c0 >> 2, k0 = ((c0 & 3) ^ ((r0 >> 1) & 3)) << 3;
  const int r1 = c1 >> 2, k1 = ((c1 & 3) ^ ((r1 >> 1) & 3)) << 3;
  const bf16* a0 = A + (size_t)(m0 + r0) * 512 + k0;
  const bf16* a1 = A + (size_t)(m0 + r1) * 512 + k1;
  const bf16* b0 = Bw + (size_t)(n0 + r0) * 512 + k0;
  const bf16* b1 = Bw + (size_t)(n0 + r1) * 512 + k1;
  const int sw = (q ^ ((fr >> 1) & 3)) << 3;

#pragma unroll
  for (int mt = 0; mt < 4; ++mt)
#pragma unroll
    for (int nt = 0; nt < 4; ++nt) { f32x4 z = {0.f, 0.f, 0.f, 0.f}; acc[mt][nt] = z; }

  auto issue = [&](int kt, int p) {
    bf16* d = lds + p * 8192;
    async16(a0 + kt, d + (c0 << 3));
    async16(a1 + kt, d + (c1 << 3));
    async16(b0 + kt, d + 4096 + (c0 << 3));
    async16(b1 + kt, d + 4096 + (c1 << 3));
  };

  issue(0, 0);
#pragma unroll
  for (int it = 0; it < 16; ++it) {
    const int p = it & 1;
    asm volatile("s_waitcnt vmcnt(0)" ::: "memory");      // buf it landed
    asm volatile("s_barrier" ::: "memory");
    if (it + 1 < 16) issue((it + 1) << 5, p ^ 1);         // WAR-safe post-barrier
    const bf16* ab = lds + p * 8192;
    const bf16* bb = ab + 4096;
    bf16x8 af[4], bfv[4];
#pragma unroll
    for (int mt = 0; mt < 4; ++mt)
      af[mt] = *(const bf16x8*)(ab + (wm + mt * 16 + fr) * 32 + sw);
#pragma unroll
    for (int nt = 0; nt < 4; ++nt)
      bfv[nt] = *(const bf16x8*)(bb + (wn + nt * 16 + fr) * 32 + sw);
#pragma unroll
    for (int mt = 0; mt < 4; ++mt)
#pragma unroll
      for (int nt = 0; nt < 4; ++nt)
        acc[mt][nt] = __builtin_amdgcn_mfma_f32_16x16x32_bf16(af[mt], bfv[nt],
                                                              acc[mt][nt], 0, 0, 0);
    asm volatile("s_waitcnt lgkmcnt(0)" ::: "memory");
  }
}
// C/D layout (verified m89/m91): col = lane&15, row = (lane>>4)*4 + reg.

// ---------------------------------------------------------------- fused phase-0
// Block ranges: [0,6536) transpose | [6536,6741) bias gather |
// [6741,7797) zero tbuf+lr | [7797,8821) lin0.
struct TEntry { const float* src; bf16* dst; int N, tile0, ntn; };
struct P0Args {
  TEntry e[11];
  const float *ba, *bo, *bVr, *bVi, *bBr, *bBi, *bD, *bUr, *bUi, *bCr, *bCi;
  float *bbigA, *bbigB, *bbigC;
  float *tbuf, *lr;
  const float *zt, *dt, *ut, *W0, *b0;
  float* s0;
};

__global__ void k_p0(P0Args a) {
  __shared__ float tile[64][65];
  const int blk = blockIdx.x;
  const int tid = threadIdx.x;

  if (blk < 6536) {                                   // ---- weight transpose
    int t = blk;
    int ei = 0;
    while (ei < 10 && t >= a.e[ei + 1].tile0) ++ei;
    const TEntry E = a.e[ei];
    int lt = t - E.tile0;
    int tk = lt / E.ntn, tn = lt - tk * E.ntn;
    int k0 = tk << 6, n0 = tn << 6;
#pragma unroll
    for (int i = 0; i < 4; ++i) {
      int idx = tid + i * 256;
      int kk = idx >> 4, c4 = (idx & 15) << 2;
      const float4 v = *(const float4*)(E.src + (size_t)(k0 + kk) * E.N + n0 + c4);
      tile[c4 + 0][kk] = v.x; tile[c4 + 1][kk] = v.y;
      tile[c4 + 2][kk] = v.z; tile[c4 + 3][kk] = v.w;
    }
    __syncthreads();
#pragma unroll
    for (int i = 0; i < 4; ++i) {
      int idx = tid + i * 256;
      int nn = idx >> 4, k4 = (idx & 15) << 2;
      bf16x4 o;
      o[0] = (bf16)tile[nn][k4 + 0]; o[1] = (bf16)tile[nn][k4 + 1];
      o[2] = (bf16)tile[nn][k4 + 2]; o[3] = (bf16)tile[nn][k4 + 3];
      *(bf16x4*)(E.dst + (size_t)(n0 + nn) * 512 + k0 + k4) = o;
    }
  } else if (blk < 6741) {                            // ---- bias gather
    int i = (blk - 6536) * 256 + tid;
    if (i < 22656) {
      float v;
      if (i < 256) v = a.ba[i];
      else if (i < 512) v = a.bo[i - 256];
      else if (i < 2560) v = a.bVr[i - 512];
      else if (i < 4608) v = a.bVi[i - 2560];
      else if (i < 12800) v = a.bBr[i - 4608];
      else if (i < 20992) v = a.bBi[i - 12800];
      else if (i < 22592) v = a.bD[i - 20992];
      else v = 0.f;
      a.bbigA[i] = v;
    }
    int j = i - 22656;
    if (j >= 0 && j < 4096) a.bbigB[j] = (j < 2048) ? a.bUr[j] : a.bUi[j - 2048];
    int m = i - (22656 + 4096);
    if (m >= 0 && m < 25600) a.bbigC[m] = (m < 12800) ? a.bCr[m] : a.bCi[m - 12800];
  } else if (blk < 7797) {                            // ---- zero tbuf (8192 f4) + lr
    int idx = (blk - 6741) * 256 + tid;
    float4 z = {0.f, 0.f, 0.f, 0.f};
    if (idx < 8192) *(float4*)(a.tbuf + idx * 4) = z;
    else            *(float4*)(a.lr + (idx - 8192) * 4) = z;   // 262144 f4
  } else {                                            // ---- lin0 (selector layer 0)
    int i = (blk - 7797) * 256 + tid;                 // 2048*128
    int b = i >> 7, c = i & 127;
    const float* w = a.W0 + c;
    const float* x = a.zt + (size_t)b * 512;
    float a0 = a.b0[c], a1 = 0.f, a2 = 0.f, a3 = 0.f;
#pragma unroll 4
    for (int k = 0; k < 512; k += 4) {
      a0 = fmaf(x[k + 0], w[(size_t)(k + 0) * 128], a0);
      a1 = fmaf(x[k + 1], w[(size_t)(k + 1) * 128], a1);
      a2 = fmaf(x[k + 2], w[(size_t)(k + 2) * 128], a2);
      a3 = fmaf(x[k + 3], w[(size_t)(k + 3) * 128], a3);
    }
    const float* u = a.ut + (size_t)b * 32;
#pragma unroll
    for (int k = 0; k < 32; k += 4) {
      a0 = fmaf(u[k + 0], w[(size_t)(512 + k + 0) * 128], a0);
      a1 = fmaf(u[k + 1], w[(size_t)(512 + k + 1) * 128], a1);
      a2 = fmaf(u[k + 2], w[(size_t)(512 + k + 2) * 128], a2);
      a3 = fmaf(u[k + 3], w[(size_t)(512 + k + 3) * 128], a3);
    }
    a0 = fmaf(a.dt[b], w[(size_t)544 * 128], a0);
    a.s0[i] = (a0 + a1) + (a2 + a3);
  }
}

// ---------------------------------------------------------------- BN stats
__global__ void k_stats(const float* __restrict__ s, float* __restrict__ mu,
                        float* __restrict__ rstd) {
  int c = blockIdx.x;                           // 128 columns
  float sm = 0.f, sq = 0.f;
  for (int r = threadIdx.x; r < 2048; r += 256) {
    float v = s[(size_t)r * 128 + c];
    sm += v; sq += v * v;
  }
#pragma unroll
  for (int o = 32; o >= 1; o >>= 1) { sm += __shfl_down(sm, o); sq += __shfl_down(sq, o); }
  __shared__ float red[8];
  int w = threadIdx.x >> 6;
  if ((threadIdx.x & 63) == 0) { red[w] = sm; red[4 + w] = sq; }
  __syncthreads();
  if (threadIdx.x == 0) {
    float S = red[0] + red[1] + red[2] + red[3];
    float Q = red[4] + red[5] + red[6] + red[7];
    float m = S * (1.f / 2048.f);
    float var = Q * (1.f / 2048.f) - m * m;    // biased var (training-mode BN)
    mu[c] = m;
    rstd[c] = rsqrtf(var + 1e-5f);
  }
}

// ---------------------------------------------------------------- lin1/lin2 (inline BN)
__global__ void k_lin1(const float* __restrict__ s0, const float* __restrict__ mu,
                       const float* __restrict__ rstd, const float* __restrict__ g,
                       const float* __restrict__ be, const float* __restrict__ W1,
                       const float* __restrict__ b1, float* __restrict__ s1) {
  int i = blockIdx.x * 256 + threadIdx.x;      // 2048*128
  int b = i >> 7, c = i & 127;
  const float* w = W1 + c;
  const float* x = s0 + (size_t)b * 128;
  float a0 = b1[c], a1 = 0.f, a2 = 0.f, a3 = 0.f;
#pragma unroll 4
  for (int k = 0; k < 128; k += 4) {
    float h0 = fmaxf(fmaf((x[k + 0] - mu[k + 0]) * rstd[k + 0], g[k + 0], be[k + 0]), 0.f);
    float h1 = fmaxf(fmaf((x[k + 1] - mu[k + 1]) * rstd[k + 1], g[k + 1], be[k + 1]), 0.f);
    float h2 = fmaxf(fmaf((x[k + 2] - mu[k + 2]) * rstd[k + 2], g[k + 2], be[k + 2]), 0.f);
    float h3 = fmaxf(fmaf((x[k + 3] - mu[k + 3]) * rstd[k + 3], g[k + 3], be[k + 3]), 0.f);
    a0 = fmaf(h0, w[(size_t)(k + 0) * 128], a0);
    a1 = fmaf(h1, w[(size_t)(k + 1) * 128], a1);
    a2 = fmaf(h2, w[(size_t)(k + 2) * 128], a2);
    a3 = fmaf(h3, w[(size_t)(k + 3) * 128], a3);
  }
  s1[i] = (a0 + a1) + (a2 + a3);
}

__global__ void k_lin2(const float* __restrict__ s1, const float* __restrict__ mu,
                       const float* __restrict__ rstd, const float* __restrict__ g,
                       const float* __restrict__ be, const float* __restrict__ W2,
                       const float* __restrict__ b2, bf16* __restrict__ hz) {
  int i = blockIdx.x * 256 + threadIdx.x;      // 2048*512
  int b = i >> 9, c = i & 511;
  const float* w = W2 + c;
  const float* x = s1 + (size_t)b * 128;
  float a0 = b2[c], a1 = 0.f, a2 = 0.f, a3 = 0.f;
#pragma unroll 4
  for (int k = 0; k < 128; k += 4) {
    float h0 = fmaxf(fmaf((x[k + 0] - mu[k + 0]) * rstd[k + 0], g[k + 0], be[k + 0]), 0.f);
    float h1 = fmaxf(fmaf((x[k + 1] - mu[k + 1]) * rstd[k + 1], g[k + 1], be[k + 1]), 0.f);
    float h2 = fmaxf(fmaf((x[k + 2] - mu[k + 2]) * rstd[k + 2], g[k + 2], be[k + 2]), 0.f);
    float h3 = fmaxf(fmaf((x[k + 3] - mu[k + 3]) * rstd[k + 3], g[k + 3], be[k + 3]), 0.f);
    a0 = fmaf(h0, w[(size_t)(k + 0) * 512], a0);
    a1 = fmaf(h1, w[(size_t)(k + 1) * 512], a1);
    a2 = fmaf(h2, w[(size_t)(k + 2) * 512], a2);
    a3 = fmaf(h3, w[(size_t)(k + 3) * 512], a3);
  }
  hz[i] = (bf16)((a0 + a1) + (a2 + a3));
}

// ---------------------------------------------------------------- phase A GEMM
// columns: [0,256) a | [256,512) o | [512,2560) Vr | [2560,4608) Vi
//          [4608,12800) Br | [12800,20992) Bi | [20992,22592) D | pad to 22656
__global__ __launch_bounds__(256) void k_gemmA(
    const bf16* __restrict__ hz, const bf16* __restrict__ WT, const float* __restrict__ bias,
    const float* __restrict__ zt, const float* __restrict__ dt, const float* __restrict__ ut,
    float* __restrict__ pa, float* __restrict__ po,
    float* __restrict__ Bzr, float* __restrict__ Bzi,
    float* __restrict__ tbuf, float* __restrict__ ytout) {
  int m0, n0;
  if (!tile_map(177, m0, n0)) return;
  __shared__ __align__(16) bf16 lds[24576];
  f32x4 acc[4][4];
  gemm_p3(hz, WT, m0, n0, lds, acc);
  const int l = threadIdx.x & 63, w = threadIdx.x >> 6;
  const int wm = (w >> 1) << 6, wn = (w & 1) << 6;
  const int fr = l & 15, quad = l >> 4;
  const int ncol = n0 + wn;

  if (n0 < 512) {                                    // ---- a / o pre-acts
    float* dst = (n0 < 256) ? pa : po;
    int cb = ncol - ((n0 < 256) ? 0 : 256);
#pragma unroll
    for (int mt = 0; mt < 4; ++mt)
#pragma unroll
      for (int j = 0; j < 4; ++j) {
        int b = m0 + wm + mt * 16 + quad * 4 + j;
#pragma unroll
        for (int nt = 0; nt < 4; ++nt) {
          int n = ncol + nt * 16 + fr;
          dst[(size_t)b * 256 + (cb + nt * 16 + fr)] = acc[mt][nt][j] + bias[n];
        }
      }
  } else if (n0 < 4608) {                            // ---- V: t = conj(V)^T z
    const bool isVr = n0 < 2560;
#pragma unroll
    for (int mt = 0; mt < 4; ++mt)
#pragma unroll
      for (int j = 0; j < 4; ++j) {
        int b = m0 + wm + mt * 16 + quad * 4 + j;
        float cre = 0.f, cim = 0.f;
#pragma unroll
        for (int nt = 0; nt < 4; ++nt) {
          int n = ncol + nt * 16 + fr;
          float v = acc[mt][nt][j] + bias[n];
          int d = ((n - 512) & 2047) >> 3;
          float zr = zt[(size_t)b * 512 + d], zi = zt[(size_t)b * 512 + 256 + d];
          if (isVr) { cre += v * zr; cim += v * zi; }
          else      { cre += v * zi; cim -= v * zr; }
        }
        cre += __shfl_xor(cre, 8);
        cim += __shfl_xor(cim, 8);
        if ((l & 8) == 0) {
          int r = fr & 7;
          atomicAdd(&tbuf[((size_t)b * 8 + r) * 2 + 0], cre);
          atomicAdd(&tbuf[((size_t)b * 8 + r) * 2 + 1], cim);
        }
      }
  } else if (n0 < 20992) {                           // ---- B: Bz = Bt @ (ut*dt)
    const bool isBr = n0 < 12800;
    float* dst = isBr ? Bzr : Bzi;
#pragma unroll
    for (int mt = 0; mt < 4; ++mt)
#pragma unroll
      for (int j = 0; j < 4; ++j) {
        int b = m0 + wm + mt * 16 + quad * 4 + j;
        float dtb = dt[b];
#pragma unroll
        for (int g = 0; g < 2; ++g) {
          float s = 0.f;
#pragma unroll
          for (int h = 0; h < 2; ++h) {
            int nt = g * 2 + h;
            int n = ncol + nt * 16 + fr;
            int base = (n - 4608) & 8191;
            float v = acc[mt][nt][j] + bias[n];
            s += v * ut[(size_t)b * 32 + (base & 31)];
          }
          s *= dtb;
          s += __shfl_xor(s, 1); s += __shfl_xor(s, 2);
          s += __shfl_xor(s, 4); s += __shfl_xor(s, 8);
          if ((l & 15) == 0) {
            int d = (((ncol + g * 32) - 4608) & 8191) >> 5;
            dst[(size_t)b * 256 + d] = s;
          }
        }
      }
  } else {                                           // ---- D: yt init
#pragma unroll
    for (int mt = 0; mt < 4; ++mt)
#pragma unroll
      for (int j = 0; j < 4; ++j) {
        int b = m0 + wm + mt * 16 + quad * 4 + j;
        float dtb = dt[b];
#pragma unroll
        for (int g = 0; g < 2; ++g) {
          float s = 0.f;
#pragma unroll
          for (int h = 0; h < 2; ++h) {
            int nt = g * 2 + h;
            int n = ncol + nt * 16 + fr;
            int base = n - 20992;
            float v = acc[mt][nt][j] + bias[n];
            s += v * ut[(size_t)b * 32 + (base & 31)];
          }
          s *= dtb;
          s += __shfl_xor(s, 1); s += __shfl_xor(s, 2);
          s += __shfl_xor(s, 4); s += __shfl_xor(s, 8);
          int nn = ((ncol + g * 32) - 20992) >> 5;
          if ((l & 15) == 0 && nn < 50) ytout[(size_t)b * 50 + nn] = s;
        }
      }
  }
}

// ---------------------------------------------------------------- phase B GEMM (U)
__global__ __launch_bounds__(256) void k_gemmB(
    const bf16* __restrict__ hz, const bf16* __restrict__ WT, const float* __restrict__ bias,
    const float* __restrict__ tbuf, float* __restrict__ lr) {
  int m0, n0;
  if (!tile_map(32, m0, n0)) return;
  __shared__ __align__(16) bf16 lds[24576];
  f32x4 acc[4][4];
  gemm_p3(hz, WT, m0, n0, lds, acc);
  const int l = threadIdx.x & 63, w = threadIdx.x >> 6;
  const int wm = (w >> 1) << 6, wn = (w & 1) << 6;
  const int fr = l & 15, quad = l >> 4;
  const int ncol = n0 + wn;
  const bool isUr = n0 < 2048;
#pragma unroll
  for (int mt = 0; mt < 4; ++mt)
#pragma unroll
    for (int j = 0; j < 4; ++j) {
      int b = m0 + wm + mt * 16 + quad * 4 + j;
#pragma unroll
      for (int nt = 0; nt < 4; ++nt) {
        int n = ncol + nt * 16 + fr;
        int base = n & 2047;
        int r = base & 7, d = base >> 3;
        float v = acc[mt][nt][j] + bias[n];
        float tre = tbuf[((size_t)b * 8 + r) * 2], tim = tbuf[((size_t)b * 8 + r) * 2 + 1];
        float cre = isUr ? v * tre : -v * tim;
        float cim = isUr ? v * tim :  v * tre;
        cre += __shfl_xor(cre, 1); cre += __shfl_xor(cre, 2); cre += __shfl_xor(cre, 4);
        cim += __shfl_xor(cim, 1); cim += __shfl_xor(cim, 2); cim += __shfl_xor(cim, 4);
        if ((l & 7) == 0) {
          atomicAdd(&lr[((size_t)b * 256 + d) * 2 + 0], cre);
          atomicAdd(&lr[((size_t)b * 256 + d) * 2 + 1], cim);
        }
      }
    }
}

// ---------------------------------------------------------------- z_next assembly
__global__ void k_assembleZ(const float* __restrict__ zt, const float* __restrict__ pa,
                            const float* __restrict__ po, const float* __restrict__ Bzr,
                            const float* __restrict__ Bzi, const float* __restrict__ lr,
                            float* __restrict__ zout, float* __restrict__ znr,
                            float* __restrict__ zni) {
  int i = blockIdx.x * 256 + threadIdx.x;      // 2048*256
  int b = i >> 8, d = i & 255;
  float a = pa[i], o = po[i];
  float e = __expf(-fabsf(a));
  float sp = fmaxf(a, 0.f) + __logf(1.f + e);   // softplus, stable (fast path)
  float mag = __expf(-sp);
  float sn = __sinf(o), cs = __cosf(o);
  float Lr = mag * cs, Li = mag * sn;
  float zr = zt[(size_t)b * 512 + d], zi = zt[(size_t)b * 512 + 256 + d];
  float re = fmaf(Lr, zr, -Li * zi) + Bzr[i] + lr[2 * i];
  float im = fmaf(Lr, zi,  Li * zr) + Bzi[i] + lr[2 * i + 1];
  zout[(size_t)b * 512 + d] = re;
  zout[(size_t)b * 512 + 256 + d] = im;
  znr[i] = re; zni[i] = im;
}

// ---------------------------------------------------------------- phase C GEMM (C)
__global__ __launch_bounds__(256, 4) void k_gemmC(
    const bf16* __restrict__ hz, const bf16* __restrict__ WT, const float* __restrict__ bias,
    const float* __restrict__ znr, const float* __restrict__ zni, float* __restrict__ ytout) {
  int m0, n0;
  if (!tile_map(200, m0, n0)) return;
  __shared__ __align__(16) bf16 lds[16384];
  f32x4 acc[4][4];
  gemm_p2(hz, WT, m0, n0, lds, acc);
  const int l = threadIdx.x & 63, w = threadIdx.x >> 6;
  const int wm = (w >> 1) << 6, wn = (w & 1) << 6;
  const int fr = l & 15, quad = l >> 4;
  const int ncol = n0 + wn;
  const bool isCr = n0 < 12800;
  const int nb = ncol - (isCr ? 0 : 12800);
  const int nn = nb >> 8;
#pragma unroll
  for (int mt = 0; mt < 4; ++mt)
#pragma unroll
    for (int j = 0; j < 4; ++j) {
      int b = m0 + wm + mt * 16 + quad * 4 + j;
      float s = 0.f;
#pragma unroll
      for (int nt = 0; nt < 4; ++nt) {
        int n = ncol + nt * 16 + fr;
        int d = (nb + nt * 16 + fr) & 255;
        float v = acc[mt][nt][j] + bias[n];
        s += isCr ? v * znr[(size_t)b * 256 + d] : -(v * zni[(size_t)b * 256 + d]);
      }
      s += __shfl_xor(s, 1); s += __shfl_xor(s, 2);
      s += __shfl_xor(s, 4); s += __shfl_xor(s, 8);
      if ((l & 15) == 0) atomicAdd(&ytout[(size_t)b * 50 + nn], s);
    }
}

// ---------------------------------------------------------------- launch
extern "C" void kernel_launch(void* const* d_in, const int* in_sizes, int n_in,
                              void* d_out, int out_size, void* d_ws, size_t ws_size,
                              hipStream_t stream) {
  (void)in_sizes; (void)n_in; (void)out_size; (void)ws_size;
  const float* zt  = (const float*)d_in[0];
  const float* dt  = (const float*)d_in[1];
  const float* ut  = (const float*)d_in[2];
  const float* W0  = (const float*)d_in[3];  const float* b0  = (const float*)d_in[4];
  const float* W1  = (const float*)d_in[5];  const float* b1  = (const float*)d_in[6];
  const float* W2  = (const float*)d_in[7];  const float* b2  = (const float*)d_in[8];
  const float* Wa  = (const float*)d_in[9];  const float* ba  = (const float*)d_in[10];
  const float* Wo  = (const float*)d_in[11]; const float* bo  = (const float*)d_in[12];
  const float* WUr = (const float*)d_in[13]; const float* bUr = (const float*)d_in[14];
  const float* WUi = (const float*)d_in[15]; const float* bUi = (const float*)d_in[16];
  const float* WVr = (const float*)d_in[17]; const float* bVr = (const float*)d_in[18];
  const float* WVi = (const float*)d_in[19]; const float* bVi = (const float*)d_in[20];
  const float* WBr = (const float*)d_in[21]; const float* bBr = (const float*)d_in[22];
  const float* WBi = (const float*)d_in[23]; const float* bBi = (const float*)d_in[24];
  const float* WCr = (const float*)d_in[25]; const float* bCr = (const float*)d_in[26];
  const float* WCi = (const float*)d_in[27]; const float* bCi = (const float*)d_in[28];
  const float* WD  = (const float*)d_in[29]; const float* bD  = (const float*)d_in[30];
  const float* g0  = (const float*)d_in[31]; const float* be0 = (const float*)d_in[32];
  const float* g1  = (const float*)d_in[33]; const float* be1 = (const float*)d_in[34];

  char* ws = (char*)d_ws;
  bf16*  WTbig = (bf16*)(ws + 0);            // [22656, 512] bf16
  bf16*  WTU   = (bf16*)(ws + 23199744);     // [4096, 512]
  bf16*  WTC   = (bf16*)(ws + 27394048);     // [25600, 512]
  bf16*  hz    = (bf16*)(ws + 53608448);     // [2048, 512]
  float* s0    = (float*)(ws + 55705600);    // [2048, 128]
  float* s1    = (float*)(ws + 56754176);    // [2048, 128]
  float* mu0   = (float*)(ws + 57802752);
  float* rstd0 = mu0 + 128;
  float* mu1   = mu0 + 256;
  float* rstd1 = mu0 + 384;
  float* bbigA = (float*)(ws + 57804800);    // [22656]
  float* bbigB = (float*)(ws + 57895424);    // [4096]
  float* bbigC = (float*)(ws + 57911808);    // [25600]
  float* pa    = (float*)(ws + 58014208);    // [2048, 256]
  float* po    = (float*)(ws + 60111360);
  float* Bzr   = (float*)(ws + 62208512);
  float* Bzi   = (float*)(ws + 64305664);
  float* tbuf  = (float*)(ws + 66402816);    // [2048, 8, 2]
  float* lr    = (float*)(ws + 66533888);    // [2048, 256, 2]
  float* znr   = (float*)(ws + 70728192);
  float* zni   = (float*)(ws + 72825344);    // ends 74,922,496
  float* zout  = (float*)d_out;
  float* ytout = zout + 2048 * 512;

  P0Args pa0;
  {
    int tile0 = 0; int idx = 0;
    auto add = [&](const float* src, bf16* dst, int N) {
      int ntn = N >> 6;
      pa0.e[idx].src = src; pa0.e[idx].dst = dst; pa0.e[idx].N = N;
      pa0.e[idx].tile0 = tile0; pa0.e[idx].ntn = ntn;
      tile0 += ntn * 8; ++idx;
    };
    add(Wa,  WTbig + (size_t)0 * 512,     256);
    add(Wo,  WTbig + (size_t)256 * 512,   256);
    add(WVr, WTbig + (size_t)512 * 512,   2048);
    add(WVi, WTbig + (size_t)2560 * 512,  2048);
    add(WBr, WTbig + (size_t)4608 * 512,  8192);
    add(WBi, WTbig + (size_t)12800 * 512, 8192);
    add(WD,  WTbig + (size_t)20992 * 512, 1600);
    add(WUr, WTU,                         2048);
    add(WUi, WTU + (size_t)2048 * 512,    2048);
    add(WCr, WTC,                         12800);
    add(WCi, WTC + (size_t)12800 * 512,   12800);
    // tile0 == 6536
  }
  pa0.ba = ba; pa0.bo = bo; pa0.bVr = bVr; pa0.bVi = bVi; pa0.bBr = bBr;
  pa0.bBi = bBi; pa0.bD = bD; pa0.bUr = bUr; pa0.bUi = bUi; pa0.bCr = bCr;
  pa0.bCi = bCi;
  pa0.bbigA = bbigA; pa0.bbigB = bbigB; pa0.bbigC = bbigC;
  pa0.tbuf = tbuf; pa0.lr = lr;
  pa0.zt = zt; pa0.dt = dt; pa0.ut = ut; pa0.W0 = W0; pa0.b0 = b0; pa0.s0 = s0;

  // 6536 transpose + 205 prep + 1056 zero + 1024 lin0 = 8821 blocks
  k_p0<<<8821, 256, 0, stream>>>(pa0);

  k_stats<<<128, 256, 0, stream>>>(s0, mu0, rstd0);
  k_lin1<<<1024, 256, 0, stream>>>(s0, mu0, rstd0, g0, be0, W1, b1, s1);
  k_stats<<<128, 256, 0, stream>>>(s1, mu1, rstd1);
  k_lin2<<<4096, 256, 0, stream>>>(s1, mu1, rstd1, g1, be1, W2, b2, hz);

  // NT=177 -> pad to 184 n-tiles; invalid tiles early-exit before any barrier.
  k_gemmA<<<184 * 16, 256, 0, stream>>>(hz, WTbig, bbigA, zt, dt, ut,
                                        pa, po, Bzr, Bzi, tbuf, ytout);
  k_gemmB<<<32 * 16, 256, 0, stream>>>(hz, WTU, bbigB, tbuf, lr);
  k_assembleZ<<<2048, 256, 0, stream>>>(zt, pa, po, Bzr, Bzi, lr, zout, znr, zni);
  k_gemmC<<<200 * 16, 256, 0, stream>>>(hz, WTC, bbigC, znr, zni, ytout);
}